// Round 11
// baseline (679.631 us; speedup 1.0000x reference)
//
#include <hip/hip_runtime.h>
#include <cstdint>
#include <cmath>

#define DI __device__ __forceinline__

constexpr int BB = 16;      // batch
constexpr int NN = 1024;    // points
constexpr int KK = 20;      // neighbors
constexpr int NPT = BB*NN;  // total points 16384
constexpr float EPSF = 1e-5f;
constexpr float NEGINF = -3.0e38f;

DI float lrelu(float x){ return x >= 0.f ? x : 0.2f * x; }
DI float dot4(const float4 a, const float4 b){ return a.x*b.x + a.y*b.y + a.z*b.z + a.w*b.w; }
DI unsigned short f2bf(float x){            // round-to-nearest-even bf16
    uint32_t u = __float_as_uint(x);
    uint32_t r = (u + 0x7fffu + ((u >> 16) & 1u)) >> 16;
    return (unsigned short)r;
}

typedef __attribute__((ext_vector_type(8))) short short8v;  // bf16x8 MFMA fragment
typedef __attribute__((ext_vector_type(4))) float f32x4;

// ---------------------------------------------------------------- transpose x [B,3,N] -> xt0 [B,N,3]
__global__ void k_transpose(const float* __restrict__ x, float* __restrict__ xt)
{
    int i = blockIdx.x * 256 + threadIdx.x;
    if (i >= NPT) return;
    int b = i >> 10, n = i & 1023;
    #pragma unroll
    for (int c = 0; c < 3; ++c) xt[i*3 + c] = x[(b*3 + c)*NN + n];
}

// ---------------------------------------------------------------- squared norms per point
__global__ void k_sqnorm(const float* __restrict__ src, int stride, int C, float* __restrict__ xx)
{
    int i = blockIdx.x * 256 + threadIdx.x;
    if (i >= NPT) return;
    const float* r = src + (size_t)i * stride;
    float s = 0.f;
    for (int c = 0; c < C; ++c){ float v = r[c]; s += v * v; }
    xx[i] = s;
}

// ---------------------------------------------------------------- kNN
// Block = 1024 threads (16 waves), 64 queries (wave -> 4 queries), grid 256.
// Distances: candidates tiled 128 at a time into XOR-swizzled LDS; queries
// via wave-uniform global (scalar) loads. Selection: T = 21st-largest via
// MSB-first radix search on order-preserving uint keys, counting with
// ballot+popcount — the 4 queries' bit-chains INTERLEAVED per bit so the
// per-bit serial latency is paid once for 4 independent chains (R10 ran
// them back-to-back and was latency-bound).
template<int C>
__global__ __launch_bounds__(1024, 4) void k_knn(const float* __restrict__ src, int stride,
                                                 const float* __restrict__ xx,
                                                 int* __restrict__ idxo)
{
    constexpr bool SMALL = (C == 3);
    constexpr int CG = SMALL ? 1 : (C / 4);
    constexpr int TS = SMALL ? 5 : C;
    __shared__ float tile[128 * TS];

    const int tid  = threadIdx.x;
    const int lane = tid & 63;
    const int wv   = __builtin_amdgcn_readfirstlane(tid >> 6);  // 0..15 uniform
    const int b  = blockIdx.x >> 4;
    const int q0 = (blockIdx.x & 15) << 6;
    const int qbase = b*NN + q0 + (wv << 2);      // wave's first query (uniform)

    // uniform query-row pointers (scalar loads, L1-resident after tile 0)
    const float* qp0 = src + (size_t)(qbase + 0)*stride;
    const float* qp1 = src + (size_t)(qbase + 1)*stride;
    const float* qp2 = src + (size_t)(qbase + 2)*stride;
    const float* qp3 = src + (size_t)(qbase + 3)*stride;

    float xxq[4];
    #pragma unroll
    for (int q = 0; q < 4; ++q) xxq[q] = xx[qbase + q];

    float val[4][16];

    #pragma unroll
    for (int t = 0; t < 8; ++t){
        __syncthreads();
        // ---- stage candidate tile t (full rows, coalesced) ----
        if constexpr (SMALL){
            for (int i = tid; i < 128*3; i += 1024){
                int row = i / 3, c = i % 3;
                tile[row*TS + c] = src[(size_t)(b*NN + t*128 + row)*stride + c];
            }
        } else {
            for (int i = tid; i < 128*CG; i += 1024){
                int row = i / CG, cg = i % CG;
                int p = cg ^ (row & (CG - 1));    // XOR swizzle
                float4 v = *(const float4*)(src + (size_t)(b*NN + t*128 + row)*stride + cg*4);
                *(float4*)(tile + row*TS + p*4) = v;
            }
        }
        __syncthreads();

        float acc[4][2];
        #pragma unroll
        for (int q = 0; q < 4; ++q){ acc[q][0] = 0.f; acc[q][1] = 0.f; }

        if constexpr (SMALL){
            float c0a = tile[lane*TS+0], c0b = tile[lane*TS+1], c0c = tile[lane*TS+2];
            float c1a = tile[(64+lane)*TS+0], c1b = tile[(64+lane)*TS+1], c1c = tile[(64+lane)*TS+2];
            float q00 = qp0[0], q01 = qp0[1], q02 = qp0[2];
            float q10 = qp1[0], q11 = qp1[1], q12 = qp1[2];
            float q20 = qp2[0], q21 = qp2[1], q22 = qp2[2];
            float q30 = qp3[0], q31 = qp3[1], q32 = qp3[2];
            acc[0][0] = q00*c0a + q01*c0b + q02*c0c;  acc[0][1] = q00*c1a + q01*c1b + q02*c1c;
            acc[1][0] = q10*c0a + q11*c0b + q12*c0c;  acc[1][1] = q10*c1a + q11*c1b + q12*c1c;
            acc[2][0] = q20*c0a + q21*c0b + q22*c0c;  acc[2][1] = q20*c1a + q21*c1b + q22*c1c;
            acc[3][0] = q30*c0a + q31*c0b + q32*c0c;  acc[3][1] = q30*c1a + q31*c1b + q32*c1c;
        } else {
            const int sw = lane & (CG - 1);
            #pragma unroll 2
            for (int cg0 = 0; cg0 < CG; ++cg0){
                float4 cf0 = *(const float4*)(tile + lane*TS      + ((cg0 ^ sw) << 2));
                float4 cf1 = *(const float4*)(tile + (64+lane)*TS + ((cg0 ^ sw) << 2));
                float4 qf0 = *(const float4*)(qp0 + (cg0 << 2));
                float4 qf1 = *(const float4*)(qp1 + (cg0 << 2));
                float4 qf2 = *(const float4*)(qp2 + (cg0 << 2));
                float4 qf3 = *(const float4*)(qp3 + (cg0 << 2));
                acc[0][0] += dot4(qf0, cf0); acc[0][1] += dot4(qf0, cf1);
                acc[1][0] += dot4(qf1, cf0); acc[1][1] += dot4(qf1, cf1);
                acc[2][0] += dot4(qf2, cf0); acc[2][1] += dot4(qf2, cf1);
                acc[3][0] += dot4(qf3, cf0); acc[3][1] += dot4(qf3, cf1);
            }
        }
        float xxm0 = xx[b*NN + t*128 + lane];
        float xxm1 = xx[b*NN + t*128 + 64 + lane];
        #pragma unroll
        for (int q = 0; q < 4; ++q){
            val[q][2*t]   = 2.f*acc[q][0] - xxq[q] - xxm0;
            val[q][2*t+1] = 2.f*acc[q][1] - xxq[q] - xxm1;
        }
    }

    // ---- selection: ballot-popcount radix-select, 4 query chains interleaved ----
    // order-preserving keys: uint order == float order
    uint32_t key[4][16];
    #pragma unroll
    for (int q = 0; q < 4; ++q)
        #pragma unroll
        for (int j = 0; j < 16; ++j){
            uint32_t u = __float_as_uint(val[q][j]);
            key[q][j] = (u & 0x80000000u) ? ~u : (u | 0x80000000u);
        }

    // greedy MSB search per query: P = max threshold with count(key >= P) >= 21
    // == exact 21st-largest key; 4 chains advanced together per bit (ILP)
    uint32_t P[4] = {0u, 0u, 0u, 0u};
    for (int bit = 31; bit >= 0; --bit){
        uint32_t msk = 1u << bit;
        int c[4];
        #pragma unroll
        for (int q = 0; q < 4; ++q){
            uint32_t cand = P[q] | msk;
            int cc = 0;
            #pragma unroll
            for (int j = 0; j < 16; ++j)
                cc += __popcll(__ballot(key[q][j] >= cand));
            c[q] = cc;
        }
        #pragma unroll
        for (int q = 0; q < 4; ++q)
            P[q] = (c[q] >= 21) ? (P[q] | msk) : P[q];
    }

    // ---- emission per query: {key > Tk} set, fill ==Tk by lowest index ----
    #pragma unroll
    for (int q = 0; q < 4; ++q){
        const int orow = (qbase + q) * KK;
        const uint32_t Tk = P[q];
        int cnt = 0;
        #pragma unroll
        for (int j = 0; j < 16; ++j) cnt += (key[q][j] > Tk) ? 1 : 0;
        int off = cnt;
        #pragma unroll
        for (int d = 1; d < 64; d <<= 1){
            int tt = __shfl_up(off, d);
            if (lane >= d) off += tt;
        }
        int total = __shfl(off, 63);
        int pos = orow + off - cnt;
        #pragma unroll
        for (int j = 0; j < 16; ++j){
            if (key[q][j] > Tk){ idxo[pos] = j*64 + lane; ++pos; }
        }
        if (total < KK){
            int rem = KK - total;
            int prior = 0;
            #pragma unroll
            for (int j = 0; j < 16; ++j){
                unsigned long long mk = __ballot(key[q][j] == Tk);
                int below = __popcll(mk & ((1ull << lane) - 1ull));
                if ((key[q][j] == Tk) && (prior + below < rem))
                    idxo[orow + total + prior + below] = j*64 + lane;
                prior += __popcll(mk);
            }
        }
    }
}

// ---------------------------------------------------------------- weight prep: W' = [Wj ; Wi-Wj]
__global__ void k_wprep(const float* __restrict__ w, int O, int C, float* __restrict__ wp)
{
    int i = blockIdx.x*256 + threadIdx.x;
    if (i >= O*C) return;
    int o = i / C, c = i % C;
    float a = w[o*2*C + c];
    float bq = w[o*2*C + C + c];
    wp[o*C + c]       = a;
    wp[(O + o)*C + c] = bq - a;
}

// ---------------------------------------------------------------- u/v GEMM (fp32: feeds next kNN, must stay exact)
template<int K, int M2, int O>
__global__ __launch_bounds__(256) void k_uvgemm(const float* __restrict__ srcp,
    const float* __restrict__ wp,
    const float* __restrict__ g, const float* __restrict__ bp,
    const float* __restrict__ mp, const float* __restrict__ vp,
    float* __restrict__ ub, float* __restrict__ xcv)
{
    constexpr int LD = 136;
    __shared__ float wl[16*LD];
    __shared__ float xl[16*LD];
    const int tid = threadIdx.x;
    const int nt = blockIdx.x & 127;
    const int mt = blockIdx.x >> 7;
    const int to = tid >> 4, tn = tid & 15;

    float acc[8][8];
    #pragma unroll
    for (int i = 0; i < 8; ++i)
        #pragma unroll
        for (int j = 0; j < 8; ++j) acc[i][j] = 0.f;

    for (int c0 = 0; c0 < K; c0 += 16){
        __syncthreads();
        #pragma unroll
        for (int p = 0; p < 2; ++p){
            int fi = tid + (p << 8);
            int row = fi >> 2, cq = (fi & 3) << 2;
            float4 wv = *(const float4*)(wp + (size_t)(mt*128 + row)*K + c0 + cq);
            wl[(cq+0)*LD + row] = wv.x;
            wl[(cq+1)*LD + row] = wv.y;
            wl[(cq+2)*LD + row] = wv.z;
            wl[(cq+3)*LD + row] = wv.w;
            float4 xv = *(const float4*)(srcp + (size_t)(nt*128 + row)*512 + c0 + cq);
            xl[(cq+0)*LD + row] = xv.x;
            xl[(cq+1)*LD + row] = xv.y;
            xl[(cq+2)*LD + row] = xv.z;
            xl[(cq+3)*LD + row] = xv.w;
        }
        __syncthreads();
        #pragma unroll
        for (int cc = 0; cc < 16; ++cc){
            float4 a0 = *(const float4*)(wl + cc*LD + to*8);
            float4 a1 = *(const float4*)(wl + cc*LD + to*8 + 4);
            float4 b0 = *(const float4*)(xl + cc*LD + tn*8);
            float4 b1 = *(const float4*)(xl + cc*LD + tn*8 + 4);
            float av[8] = {a0.x,a0.y,a0.z,a0.w,a1.x,a1.y,a1.z,a1.w};
            float bv[8] = {b0.x,b0.y,b0.z,b0.w,b1.x,b1.y,b1.z,b1.w};
            #pragma unroll
            for (int i = 0; i < 8; ++i)
                #pragma unroll
                for (int j = 0; j < 8; ++j) acc[i][j] += av[i]*bv[j];
        }
    }

    const int mbase = mt*128 + to*8;
    const bool isu = mbase < O;
    float mult[8], add[8];
    #pragma unroll
    for (int i = 0; i < 8; ++i){
        int m = mbase + i;
        if (isu){
            float s = g[m] / sqrtf(vp[m] + EPSF);
            mult[i] = (s >= 0.f) ? 1.f : -1.f;
            add[i]  = 0.f;
        } else {
            int o = m - O;
            float s = g[o] / sqrtf(vp[o] + EPSF);
            mult[i] = s;
            add[i]  = bp[o] - mp[o]*s;
        }
    }
    #pragma unroll
    for (int j = 0; j < 8; ++j){
        int pt = nt*128 + tn*8 + j;
        float4 v0, v1;
        v0.x = fmaf(mult[0], acc[0][j], add[0]);
        v0.y = fmaf(mult[1], acc[1][j], add[1]);
        v0.z = fmaf(mult[2], acc[2][j], add[2]);
        v0.w = fmaf(mult[3], acc[3][j], add[3]);
        v1.x = fmaf(mult[4], acc[4][j], add[4]);
        v1.y = fmaf(mult[5], acc[5][j], add[5]);
        v1.z = fmaf(mult[6], acc[6][j], add[6]);
        v1.w = fmaf(mult[7], acc[7][j], add[7]);
        if (isu){
            float* d = ub + (size_t)pt*O + mbase;
            *(float4*)(d)     = v0;
            *(float4*)(d + 4) = v1;
        } else {
            float* d = xcv + (size_t)pt*512 + (mbase - O);
            *(float4*)(d)     = v0;
            *(float4*)(d + 4) = v1;
        }
    }
}

// ---------------------------------------------------------------- layer-1 u/v (C=3) direct
__global__ __launch_bounds__(256) void k_uv3(const float* __restrict__ xt,
    const float* __restrict__ wp,
    const float* __restrict__ g, const float* __restrict__ bp,
    const float* __restrict__ mp, const float* __restrict__ vp,
    float* __restrict__ ub, float* __restrict__ xcv)
{
    __shared__ float wpl[128*3];
    __shared__ float mult[128], add[128];
    const int tid = threadIdx.x;
    if (tid < 128){
        int m = tid;
        if (m < 64){
            float s = g[m] / sqrtf(vp[m] + EPSF);
            mult[m] = (s >= 0.f) ? 1.f : -1.f;
            add[m]  = 0.f;
        } else {
            int o = m - 64;
            float s = g[o] / sqrtf(vp[o] + EPSF);
            mult[m] = s;
            add[m]  = bp[o] - mp[o]*s;
        }
    }
    for (int i = tid; i < 128*3; i += 256) wpl[i] = wp[i];
    __syncthreads();

    const int ptl = tid >> 5, mg = tid & 31;
    const int m0 = mg * 4;
    const int pt = blockIdx.x*8 + ptl;
    float x0 = xt[pt*3+0], x1 = xt[pt*3+1], x2 = xt[pt*3+2];
    float4 v4;
    float tmp[4];
    #pragma unroll
    for (int r = 0; r < 4; ++r){
        int m = m0 + r;
        float a = wpl[m*3+0]*x0 + wpl[m*3+1]*x1 + wpl[m*3+2]*x2;
        tmp[r] = fmaf(mult[m], a, add[m]);
    }
    v4.x = tmp[0]; v4.y = tmp[1]; v4.z = tmp[2]; v4.w = tmp[3];
    if (m0 < 64) *(float4*)(ub + (size_t)pt*64 + m0) = v4;
    else         *(float4*)(xcv + (size_t)pt*512 + (m0 - 64)) = v4;
}

// ---------------------------------------------------------------- combine: out = lrelu(|s| * max_k u'[j_k] + v')
template<int O>
__global__ __launch_bounds__(256) void k_edgemax(const float* __restrict__ ub,
    const int* __restrict__ idxg,
    const float* __restrict__ g, const float* __restrict__ vp,
    float* __restrict__ xcv)
{
    constexpr int TPP = O / 4;
    constexpr int PPB = 256 / TPP;
    const int tid = threadIdx.x;
    const int pt  = blockIdx.x*PPB + tid / TPP;
    const int oq  = (tid % TPP) * 4;
    const int bb  = pt & ~(NN-1);

    int nb[KK];
    #pragma unroll
    for (int k = 0; k < KK; ++k) nb[k] = idxg[pt*KK + k];

    float4 mx = *(const float4*)(ub + (size_t)(bb + nb[0])*O + oq);
    #pragma unroll
    for (int k = 1; k < KK; ++k){
        float4 u = *(const float4*)(ub + (size_t)(bb + nb[k])*O + oq);
        mx.x = fmaxf(mx.x, u.x); mx.y = fmaxf(mx.y, u.y);
        mx.z = fmaxf(mx.z, u.z); mx.w = fmaxf(mx.w, u.w);
    }
    float4 gv = *(const float4*)(g + oq);
    float4 vv = *(const float4*)(vp + oq);
    float4 as;
    as.x = fabsf(gv.x / sqrtf(vv.x + EPSF));
    as.y = fabsf(gv.y / sqrtf(vv.y + EPSF));
    as.z = fabsf(gv.z / sqrtf(vv.z + EPSF));
    as.w = fabsf(gv.w / sqrtf(vv.w + EPSF));
    float* d = xcv + (size_t)pt*512 + oq;
    float4 vr = *(const float4*)(d);
    float4 y;
    y.x = lrelu(fmaf(as.x, mx.x, vr.x));
    y.y = lrelu(fmaf(as.y, mx.y, vr.y));
    y.z = lrelu(fmaf(as.z, mx.z, vr.z));
    y.w = lrelu(fmaf(as.w, mx.w, vr.w));
    *(float4*)(d) = y;
}

// ---------------------------------------------------------------- fp32 -> bf16 cast (8 elems/thread)
__global__ void k_castbf(const float* __restrict__ s, unsigned short* __restrict__ d, int n8)
{
    int i = blockIdx.x*256 + threadIdx.x;
    if (i >= n8) return;
    const float4* sp = (const float4*)s + (size_t)i*2;
    float4 a = sp[0], b = sp[1];
    union { unsigned short u[8]; uint4 v; } o;
    o.u[0] = f2bf(a.x); o.u[1] = f2bf(a.y); o.u[2] = f2bf(a.z); o.u[3] = f2bf(a.w);
    o.u[4] = f2bf(b.x); o.u[5] = f2bf(b.y); o.u[6] = f2bf(b.z); o.u[7] = f2bf(b.w);
    *((uint4*)d + i) = o.v;
}

// ---------------------------------------------------------------- conv5 bf16 MFMA GEMM + BN + LReLU + pool partials
__global__ __launch_bounds__(256) void k_conv5mfma(const unsigned short* __restrict__ xcb,
    const unsigned short* __restrict__ w5b,
    const float* __restrict__ g, const float* __restrict__ bp,
    const float* __restrict__ mp, const float* __restrict__ vp,
    float* __restrict__ pmax, float* __restrict__ psum)
{
    __shared__ __align__(16) short lA[128*32];
    __shared__ __align__(16) short lB[128*32];
    __shared__ float scl[128], adl[128];
    __shared__ float red[2][128][2];

    const int tid = threadIdx.x;
    const int lane = tid & 63, wave = tid >> 6;
    const int wm = wave >> 1, wn = wave & 1;
    const int b  = blockIdx.x >> 6;
    const int mt = (blockIdx.x >> 3) & 7;
    const int nt = blockIdx.x & 7;

    if (tid < 128){
        int o = mt*128 + tid;
        float s = g[o] / sqrtf(vp[o] + EPSF);
        scl[tid] = s;
        adl[tid] = bp[o] - mp[o]*s;
    }

    f32x4 acc[4][4];
    #pragma unroll
    for (int i = 0; i < 4; ++i)
        #pragma unroll
        for (int j = 0; j < 4; ++j) acc[i][j] = (f32x4){0.f,0.f,0.f,0.f};

    const unsigned short* gA = w5b + (size_t)(mt*128)*512;
    const unsigned short* gB = xcb + (size_t)(b*1024 + nt*128)*512;

    for (int ks = 0; ks < 16; ++ks){
        __syncthreads();
        #pragma unroll
        for (int p = 0; p < 2; ++p){
            int off = p*256 + tid;
            int row = off >> 2;
            int slot = off & 3;
            int ssl = slot ^ (row & 3);
            *(uint4*)(lA + row*32 + ssl*8) = *(const uint4*)(gA + (size_t)row*512 + ks*32 + slot*8);
            *(uint4*)(lB + row*32 + ssl*8) = *(const uint4*)(gB + (size_t)row*512 + ks*32 + slot*8);
        }
        __syncthreads();

        short8v afr[4], bfr[4];
        #pragma unroll
        for (int i = 0; i < 4; ++i){
            int row = wm*64 + i*16 + (lane & 15);
            int sl  = (lane >> 4) ^ (row & 3);
            afr[i] = *(const short8v*)(lA + row*32 + sl*8);
        }
        #pragma unroll
        for (int j = 0; j < 4; ++j){
            int row = wn*64 + j*16 + (lane & 15);
            int sl  = (lane >> 4) ^ (row & 3);
            bfr[j] = *(const short8v*)(lB + row*32 + sl*8);
        }
        #pragma unroll
        for (int i = 0; i < 4; ++i)
            #pragma unroll
            for (int j = 0; j < 4; ++j)
                acc[i][j] = __builtin_amdgcn_mfma_f32_16x16x32_bf16(afr[i], bfr[j], acc[i][j], 0, 0, 0);
    }

    float emx[4][4], esm[4][4];
    #pragma unroll
    for (int i = 0; i < 4; ++i){
        #pragma unroll
        for (int r = 0; r < 4; ++r){
            int m_loc = wm*64 + i*16 + (lane >> 4)*4 + r;
            float s = scl[m_loc], t = adl[m_loc];
            float mx = NEGINF, sm = 0.f;
            #pragma unroll
            for (int j = 0; j < 4; ++j){
                float y = lrelu(fmaf(acc[i][j][r], s, t));
                mx = fmaxf(mx, y); sm += y;
            }
            #pragma unroll
            for (int d = 1; d < 16; d <<= 1){
                mx = fmaxf(mx, __shfl_xor(mx, d));
                sm += __shfl_xor(sm, d);
            }
            emx[i][r] = mx; esm[i][r] = sm;
        }
    }
    if ((lane & 15) == 0){
        #pragma unroll
        for (int i = 0; i < 4; ++i)
            #pragma unroll
            for (int r = 0; r < 4; ++r){
                int m_loc = wm*64 + i*16 + (lane >> 4)*4 + r;
                red[wn][m_loc][0] = emx[i][r];
                red[wn][m_loc][1] = esm[i][r];
            }
    }
    __syncthreads();
    if (tid < 128){
        float mx = fmaxf(red[0][tid][0], red[1][tid][0]);
        float sm = red[0][tid][1] + red[1][tid][1];
        int o = mt*128 + tid;
        pmax[(size_t)(b*NN + o)*8 + nt] = mx;
        psum[(size_t)(b*NN + o)*8 + nt] = sm;
    }
}

__global__ void k_poolfin(const float* __restrict__ pmax, const float* __restrict__ psum,
                          float* __restrict__ p)
{
    int i = blockIdx.x*256 + threadIdx.x;
    if (i >= NPT) return;
    int b = i >> 10, o = i & 1023;
    float mx = NEGINF, sm = 0.f;
    #pragma unroll
    for (int t = 0; t < 8; ++t){ mx = fmaxf(mx, pmax[(size_t)i*8 + t]); sm += psum[(size_t)i*8 + t]; }
    p[b*2048 + o]        = mx;
    p[b*2048 + 1024 + o] = sm * (1.f/1024.f);
}

// ---------------------------------------------------------------- small FC layers
template<int IN, int O, bool HASBN, bool HASBIAS>
__global__ void k_fc(const float* __restrict__ in, const float* __restrict__ W,
                     const float* __restrict__ bias,
                     const float* __restrict__ g, const float* __restrict__ bp,
                     const float* __restrict__ mp, const float* __restrict__ vp,
                     float* __restrict__ out)
{
    int i = blockIdx.x*256 + threadIdx.x;
    if (i >= BB*O) return;
    int b = i / O, o = i % O;
    const float* wr = W  + (size_t)o*IN;
    const float* ir = in + (size_t)b*IN;
    float s = 0.f;
    #pragma unroll 4
    for (int c = 0; c < IN; c += 4){
        float4 a = *(const float4*)(wr + c);
        float4 x = *(const float4*)(ir + c);
        s += dot4(a, x);
    }
    if (HASBIAS) s += bias[o];
    if (HASBN){
        float sc = g[o] / sqrtf(vp[o] + EPSF);
        s = (s - mp[o])*sc + bp[o];
        s = lrelu(s);
    }
    out[(size_t)b*O + o] = s;
}

// ---------------------------------------------------------------- launch
extern "C" void kernel_launch(void* const* d_in, const int* in_sizes, int n_in,
                              void* d_out, int out_size, void* d_ws, size_t ws_size,
                              hipStream_t stream)
{
    (void)in_sizes; (void)n_in; (void)out_size; (void)ws_size;
    const float* x   = (const float*)d_in[0];
    const float* w1  = (const float*)d_in[1];
    const float* w2  = (const float*)d_in[2];
    const float* w3  = (const float*)d_in[3];
    const float* w4  = (const float*)d_in[4];
    const float* w5  = (const float*)d_in[5];
    const float* wl1 = (const float*)d_in[6];
    const float* wl2 = (const float*)d_in[7];
    const float* wl3 = (const float*)d_in[8];
    const float* bl2 = (const float*)d_in[9];
    const float* bl3 = (const float*)d_in[10];
    const float* g1 = (const float*)d_in[11]; const float* b1 = (const float*)d_in[12];
    const float* m1 = (const float*)d_in[13]; const float* v1 = (const float*)d_in[14];
    const float* g2 = (const float*)d_in[15]; const float* b2 = (const float*)d_in[16];
    const float* m2 = (const float*)d_in[17]; const float* v2 = (const float*)d_in[18];
    const float* g3 = (const float*)d_in[19]; const float* b3 = (const float*)d_in[20];
    const float* m3 = (const float*)d_in[21]; const float* v3 = (const float*)d_in[22];
    const float* g4 = (const float*)d_in[23]; const float* b4 = (const float*)d_in[24];
    const float* m4 = (const float*)d_in[25]; const float* v4 = (const float*)d_in[26];
    const float* g5 = (const float*)d_in[27]; const float* b5 = (const float*)d_in[28];
    const float* m5 = (const float*)d_in[29]; const float* v5 = (const float*)d_in[30];
    const float* g6 = (const float*)d_in[31]; const float* b6 = (const float*)d_in[32];
    const float* m6 = (const float*)d_in[33]; const float* v6 = (const float*)d_in[34];
    const float* g7 = (const float*)d_in[35]; const float* b7 = (const float*)d_in[36];
    const float* m7 = (const float*)d_in[37]; const float* v7 = (const float*)d_in[38];

    float* wsf  = (float*)d_ws;
    float* xt0  = wsf;                    // 49152
    float* xc   = xt0 + 49152;            // 8388608
    float* xx   = xc + 8388608;           // 16384
    int*   idx  = (int*)(xx + 16384);     // 327680 ints
    float* pmax = (float*)(idx + 327680); // 131072
    float* psum = pmax + 131072;          // 131072
    float* p    = psum + 131072;          // 32768
    float* h1   = p + 32768;              // 8192
    float* h2   = h1 + 8192;              // 4096
    float* ub   = h2 + 4096;              // 4194304
    float* wp   = ub + 4194304;           // 65536
    unsigned short* xcb = (unsigned short*)ub;   // bf16 alias (ub dead by conv5)
    unsigned short* w5b = (unsigned short*)idx;  // bf16 alias (idx dead by conv5)

    k_transpose<<<64, 256, 0, stream>>>(x, xt0);

    // block 1: C=3 -> O=64 (channels 0..63)
    k_sqnorm<<<64, 256, 0, stream>>>(xt0, 3, 3, xx);
    k_knn<3><<<256, 1024, 0, stream>>>(xt0, 3, xx, idx);
    k_wprep<<<1, 256, 0, stream>>>(w1, 64, 3, wp);
    k_uv3<<<2048, 256, 0, stream>>>(xt0, wp, g1, b1, m1, v1, ub, xc);
    k_edgemax<64><<<1024, 256, 0, stream>>>(ub, idx, g1, v1, xc);

    // block 2: C=64 -> O=64 (channels 64..127)
    k_sqnorm<<<64, 256, 0, stream>>>(xc, 512, 64, xx);
    k_knn<64><<<256, 1024, 0, stream>>>(xc, 512, xx, idx);
    k_wprep<<<16, 256, 0, stream>>>(w2, 64, 64, wp);
    k_uvgemm<64, 128, 64><<<128, 256, 0, stream>>>(xc, wp, g2, b2, m2, v2, ub, xc + 64);
    k_edgemax<64><<<1024, 256, 0, stream>>>(ub, idx, g2, v2, xc + 64);

    // block 3: C=64 -> O=128 (channels 128..255)
    k_sqnorm<<<64, 256, 0, stream>>>(xc + 64, 512, 64, xx);
    k_knn<64><<<256, 1024, 0, stream>>>(xc + 64, 512, xx, idx);
    k_wprep<<<32, 256, 0, stream>>>(w3, 128, 64, wp);
    k_uvgemm<64, 256, 128><<<256, 256, 0, stream>>>(xc + 64, wp, g3, b3, m3, v3, ub, xc + 128);
    k_edgemax<128><<<2048, 256, 0, stream>>>(ub, idx, g3, v3, xc + 128);

    // block 4: C=128 -> O=256 (channels 256..511)
    k_sqnorm<<<64, 256, 0, stream>>>(xc + 128, 512, 128, xx);
    k_knn<128><<<256, 1024, 0, stream>>>(xc + 128, 512, xx, idx);
    k_wprep<<<128, 256, 0, stream>>>(w4, 256, 128, wp);
    k_uvgemm<128, 512, 256><<<512, 256, 0, stream>>>(xc + 128, wp, g4, b4, m4, v4, ub, xc + 256);
    k_edgemax<256><<<4096, 256, 0, stream>>>(ub, idx, g4, v4, xc + 256);

    // conv5: cast to bf16 (ub/idx now dead), MFMA GEMM + fused BN/LReLU/pool
    k_castbf<<<4096, 256, 0, stream>>>(xc, xcb, 1048576);
    k_castbf<<<256, 256, 0, stream>>>(w5, w5b, 65536);
    k_conv5mfma<<<1024, 256, 0, stream>>>(xcb, w5b, g5, b5, m5, v5, pmax, psum);
    k_poolfin<<<64, 256, 0, stream>>>(pmax, psum, p);

    // FC head
    k_fc<2048, 512, true,  false><<<32, 256, 0, stream>>>(p,  wl1, nullptr, g6, b6, m6, v6, h1);
    k_fc<512,  256, true,  true ><<<16, 256, 0, stream>>>(h1, wl2, bl2,     g7, b7, m7, v7, h2);
    k_fc<256,  101, false, true ><<<7,  256, 0, stream>>>(h2, wl3, bl3, nullptr, nullptr, nullptr, nullptr, (float*)d_out);
}

// Round 12
// 619.523 us; speedup vs baseline: 1.0970x; 1.0970x over previous
//
#include <hip/hip_runtime.h>
#include <cstdint>
#include <cmath>

#define DI __device__ __forceinline__

constexpr int BB = 16;      // batch
constexpr int NN = 1024;    // points
constexpr int KK = 20;      // neighbors
constexpr int NPT = BB*NN;  // total points 16384
constexpr float EPSF = 1e-5f;
constexpr float NEGINF = -3.0e38f;

DI float lrelu(float x){ return x >= 0.f ? x : 0.2f * x; }
DI float dot4(const float4 a, const float4 b){ return a.x*b.x + a.y*b.y + a.z*b.z + a.w*b.w; }
DI unsigned short f2bf(float x){            // round-to-nearest-even bf16
    uint32_t u = __float_as_uint(x);
    uint32_t r = (u + 0x7fffu + ((u >> 16) & 1u)) >> 16;
    return (unsigned short)r;
}

typedef __attribute__((ext_vector_type(8))) short short8v;  // bf16x8 MFMA fragment
typedef __attribute__((ext_vector_type(4))) float f32x4;

// ---------------------------------------------------------------- transpose x [B,3,N] -> xt0 [B,N,3]
__global__ void k_transpose(const float* __restrict__ x, float* __restrict__ xt)
{
    int i = blockIdx.x * 256 + threadIdx.x;
    if (i >= NPT) return;
    int b = i >> 10, n = i & 1023;
    #pragma unroll
    for (int c = 0; c < 3; ++c) xt[i*3 + c] = x[(b*3 + c)*NN + n];
}

// ---------------------------------------------------------------- squared norms per point
__global__ void k_sqnorm(const float* __restrict__ src, int stride, int C, float* __restrict__ xx)
{
    int i = blockIdx.x * 256 + threadIdx.x;
    if (i >= NPT) return;
    const float* r = src + (size_t)i * stride;
    float s = 0.f;
    for (int c = 0; c < C; ++c){ float v = r[c]; s += v * v; }
    xx[i] = s;
}

// ---------------------------------------------------------------- kNN
// Block = 1024 threads (16 waves), 64 queries (wave -> 4 queries), grid 256
// (R8 best-measured structure). Candidates tiled 128 at a time into
// XOR-swizzled LDS; queries wave-uniform global (scalar) loads. Selection:
// per-lane bitonic sort (values only) + 21-round tournament for
// T = 21st-largest; the two query-pairs' chains run INTERLEAVED for shfl
// ILP (validated in R9; here at full occupancy).
template<int C>
__global__ __launch_bounds__(1024, 4) void k_knn(const float* __restrict__ src, int stride,
                                                 const float* __restrict__ xx,
                                                 int* __restrict__ idxo)
{
    constexpr bool SMALL = (C == 3);
    constexpr int CG = SMALL ? 1 : (C / 4);
    constexpr int TS = SMALL ? 5 : C;
    __shared__ float tile[128 * TS];

    const int tid  = threadIdx.x;
    const int lane = tid & 63;
    const int wv   = __builtin_amdgcn_readfirstlane(tid >> 6);  // 0..15 uniform
    const int b  = blockIdx.x >> 4;
    const int q0 = (blockIdx.x & 15) << 6;
    const int qbase = b*NN + q0 + (wv << 2);      // wave's first query (uniform)

    const float* qp0 = src + (size_t)(qbase + 0)*stride;
    const float* qp1 = src + (size_t)(qbase + 1)*stride;
    const float* qp2 = src + (size_t)(qbase + 2)*stride;
    const float* qp3 = src + (size_t)(qbase + 3)*stride;

    float xxq[4];
    #pragma unroll
    for (int q = 0; q < 4; ++q) xxq[q] = xx[qbase + q];

    float val[4][16];

    #pragma unroll
    for (int t = 0; t < 8; ++t){
        __syncthreads();
        if constexpr (SMALL){
            for (int i = tid; i < 128*3; i += 1024){
                int row = i / 3, c = i % 3;
                tile[row*TS + c] = src[(size_t)(b*NN + t*128 + row)*stride + c];
            }
        } else {
            for (int i = tid; i < 128*CG; i += 1024){
                int row = i / CG, cg = i % CG;
                int p = cg ^ (row & (CG - 1));    // XOR swizzle
                float4 v = *(const float4*)(src + (size_t)(b*NN + t*128 + row)*stride + cg*4);
                *(float4*)(tile + row*TS + p*4) = v;
            }
        }
        __syncthreads();

        float acc[4][2];
        #pragma unroll
        for (int q = 0; q < 4; ++q){ acc[q][0] = 0.f; acc[q][1] = 0.f; }

        if constexpr (SMALL){
            float c0a = tile[lane*TS+0], c0b = tile[lane*TS+1], c0c = tile[lane*TS+2];
            float c1a = tile[(64+lane)*TS+0], c1b = tile[(64+lane)*TS+1], c1c = tile[(64+lane)*TS+2];
            float q00 = qp0[0], q01 = qp0[1], q02 = qp0[2];
            float q10 = qp1[0], q11 = qp1[1], q12 = qp1[2];
            float q20 = qp2[0], q21 = qp2[1], q22 = qp2[2];
            float q30 = qp3[0], q31 = qp3[1], q32 = qp3[2];
            acc[0][0] = q00*c0a + q01*c0b + q02*c0c;  acc[0][1] = q00*c1a + q01*c1b + q02*c1c;
            acc[1][0] = q10*c0a + q11*c0b + q12*c0c;  acc[1][1] = q10*c1a + q11*c1b + q12*c1c;
            acc[2][0] = q20*c0a + q21*c0b + q22*c0c;  acc[2][1] = q20*c1a + q21*c1b + q22*c1c;
            acc[3][0] = q30*c0a + q31*c0b + q32*c0c;  acc[3][1] = q30*c1a + q31*c1b + q32*c1c;
        } else {
            const int sw = lane & (CG - 1);
            #pragma unroll 2
            for (int cg0 = 0; cg0 < CG; ++cg0){
                float4 cf0 = *(const float4*)(tile + lane*TS      + ((cg0 ^ sw) << 2));
                float4 cf1 = *(const float4*)(tile + (64+lane)*TS + ((cg0 ^ sw) << 2));
                float4 qf0 = *(const float4*)(qp0 + (cg0 << 2));
                float4 qf1 = *(const float4*)(qp1 + (cg0 << 2));
                float4 qf2 = *(const float4*)(qp2 + (cg0 << 2));
                float4 qf3 = *(const float4*)(qp3 + (cg0 << 2));
                acc[0][0] += dot4(qf0, cf0); acc[0][1] += dot4(qf0, cf1);
                acc[1][0] += dot4(qf1, cf0); acc[1][1] += dot4(qf1, cf1);
                acc[2][0] += dot4(qf2, cf0); acc[2][1] += dot4(qf2, cf1);
                acc[3][0] += dot4(qf3, cf0); acc[3][1] += dot4(qf3, cf1);
            }
        }
        float xxm0 = xx[b*NN + t*128 + lane];
        float xxm1 = xx[b*NN + t*128 + 64 + lane];
        #pragma unroll
        for (int q = 0; q < 4; ++q){
            val[q][2*t]   = 2.f*acc[q][0] - xxq[q] - xxm0;
            val[q][2*t+1] = 2.f*acc[q][1] - xxq[q] - xxm1;
        }
    }

    // ---- selection: pairs of queries interleaved for shfl ILP ----
    #pragma unroll
    for (int qq = 0; qq < 4; qq += 2){
        float s0[16], s1[16];
        #pragma unroll
        for (int j = 0; j < 16; ++j){ s0[j] = val[qq][j]; s1[j] = val[qq+1][j]; }

        // bitonic sort descending (values only, static indices) — both lists
        #pragma unroll
        for (int k = 2; k <= 16; k <<= 1){
            #pragma unroll
            for (int jj = k >> 1; jj > 0; jj >>= 1){
                #pragma unroll
                for (int i = 0; i < 16; ++i){
                    int l = i ^ jj;
                    if (l > i){
                        bool up = ((i & k) == 0);
                        float a0 = s0[i], c0 = s0[l];
                        float mx0 = fmaxf(a0, c0), mn0 = fminf(a0, c0);
                        s0[i] = up ? mx0 : mn0;  s0[l] = up ? mn0 : mx0;
                        float a1 = s1[i], c1 = s1[l];
                        float mx1 = fmaxf(a1, c1), mn1 = fminf(a1, c1);
                        s1[i] = up ? mx1 : mn1;  s1[l] = up ? mn1 : mx1;
                    }
                }
            }
        }

        // 21 paired tournament rounds -> T = 21st-largest (multiset rank)
        float T0 = NEGINF, T1 = NEGINF;
        for (int it = 0; it < 21; ++it){
            float m0 = s0[0], m1 = s1[0];
            #pragma unroll
            for (int d = 1; d < 64; d <<= 1){
                float p0 = __shfl_xor(m0, d);
                float p1 = __shfl_xor(m1, d);
                m0 = fmaxf(m0, p0);
                m1 = fmaxf(m1, p1);
            }
            T0 = m0; T1 = m1;
            unsigned long long mk0 = __ballot(s0[0] == m0);
            unsigned long long mk1 = __ballot(s1[0] == m1);
            bool a0 = (lane == __ffsll(mk0) - 1);
            bool a1 = (lane == __ffsll(mk1) - 1);
            #pragma unroll
            for (int j = 0; j < 15; ++j){
                s0[j] = a0 ? s0[j+1] : s0[j];
                s1[j] = a1 ? s1[j+1] : s1[j];
            }
            s0[15] = a0 ? NEGINF : s0[15];
            s1[15] = a1 ? NEGINF : s1[15];
        }

        // emit {val > T} (order irrelevant downstream), fill ==T by lowest index
        #pragma unroll
        for (int h = 0; h < 2; ++h){
            const int q = qq + h;
            const float T = h ? T1 : T0;
            const int orow = (qbase + q) * KK;
            int cnt = 0;
            #pragma unroll
            for (int j = 0; j < 16; ++j) cnt += (val[q][j] > T) ? 1 : 0;
            int off = cnt;
            #pragma unroll
            for (int d = 1; d < 64; d <<= 1){
                int tt = __shfl_up(off, d);
                if (lane >= d) off += tt;
            }
            int total = __shfl(off, 63);
            int pos = orow + off - cnt;
            #pragma unroll
            for (int j = 0; j < 16; ++j){
                if (val[q][j] > T){ idxo[pos] = j*64 + lane; ++pos; }
            }
            if (total < KK){
                int rem = KK - total;
                int prior = 0;
                #pragma unroll
                for (int j = 0; j < 16; ++j){
                    unsigned long long mk = __ballot(val[q][j] == T);
                    int below = __popcll(mk & ((1ull << lane) - 1ull));
                    if ((val[q][j] == T) && (prior + below < rem))
                        idxo[orow + total + prior + below] = j*64 + lane;
                    prior += __popcll(mk);
                }
            }
        }
    }
}

// ---------------------------------------------------------------- weight prep: W' = [Wj ; Wi-Wj]
__global__ void k_wprep(const float* __restrict__ w, int O, int C, float* __restrict__ wp)
{
    int i = blockIdx.x*256 + threadIdx.x;
    if (i >= O*C) return;
    int o = i / C, c = i % C;
    float a = w[o*2*C + c];
    float bq = w[o*2*C + C + c];
    wp[o*C + c]       = a;
    wp[(O + o)*C + c] = bq - a;
}

// ---------------------------------------------------------------- u/v GEMM (fp32 math; u-rows optionally stored bf16)
template<int K, int M2, int O, bool UB16>
__global__ __launch_bounds__(256) void k_uvgemm(const float* __restrict__ srcp,
    const float* __restrict__ wp,
    const float* __restrict__ g, const float* __restrict__ bp,
    const float* __restrict__ mp, const float* __restrict__ vp,
    float* __restrict__ ub, float* __restrict__ xcv)
{
    constexpr int LD = 136;
    __shared__ float wl[16*LD];
    __shared__ float xl[16*LD];
    const int tid = threadIdx.x;
    const int nt = blockIdx.x & 127;
    const int mt = blockIdx.x >> 7;
    const int to = tid >> 4, tn = tid & 15;

    float acc[8][8];
    #pragma unroll
    for (int i = 0; i < 8; ++i)
        #pragma unroll
        for (int j = 0; j < 8; ++j) acc[i][j] = 0.f;

    for (int c0 = 0; c0 < K; c0 += 16){
        __syncthreads();
        #pragma unroll
        for (int p = 0; p < 2; ++p){
            int fi = tid + (p << 8);
            int row = fi >> 2, cq = (fi & 3) << 2;
            float4 wv = *(const float4*)(wp + (size_t)(mt*128 + row)*K + c0 + cq);
            wl[(cq+0)*LD + row] = wv.x;
            wl[(cq+1)*LD + row] = wv.y;
            wl[(cq+2)*LD + row] = wv.z;
            wl[(cq+3)*LD + row] = wv.w;
            float4 xv = *(const float4*)(srcp + (size_t)(nt*128 + row)*512 + c0 + cq);
            xl[(cq+0)*LD + row] = xv.x;
            xl[(cq+1)*LD + row] = xv.y;
            xl[(cq+2)*LD + row] = xv.z;
            xl[(cq+3)*LD + row] = xv.w;
        }
        __syncthreads();
        #pragma unroll
        for (int cc = 0; cc < 16; ++cc){
            float4 a0 = *(const float4*)(wl + cc*LD + to*8);
            float4 a1 = *(const float4*)(wl + cc*LD + to*8 + 4);
            float4 b0 = *(const float4*)(xl + cc*LD + tn*8);
            float4 b1 = *(const float4*)(xl + cc*LD + tn*8 + 4);
            float av[8] = {a0.x,a0.y,a0.z,a0.w,a1.x,a1.y,a1.z,a1.w};
            float bv[8] = {b0.x,b0.y,b0.z,b0.w,b1.x,b1.y,b1.z,b1.w};
            #pragma unroll
            for (int i = 0; i < 8; ++i)
                #pragma unroll
                for (int j = 0; j < 8; ++j) acc[i][j] += av[i]*bv[j];
        }
    }

    const int mbase = mt*128 + to*8;
    const bool isu = mbase < O;
    float mult[8], add[8];
    #pragma unroll
    for (int i = 0; i < 8; ++i){
        int m = mbase + i;
        if (isu){
            float s = g[m] / sqrtf(vp[m] + EPSF);
            mult[i] = (s >= 0.f) ? 1.f : -1.f;
            add[i]  = 0.f;
        } else {
            int o = m - O;
            float s = g[o] / sqrtf(vp[o] + EPSF);
            mult[i] = s;
            add[i]  = bp[o] - mp[o]*s;
        }
    }
    #pragma unroll
    for (int j = 0; j < 8; ++j){
        int pt = nt*128 + tn*8 + j;
        float4 v0, v1;
        v0.x = fmaf(mult[0], acc[0][j], add[0]);
        v0.y = fmaf(mult[1], acc[1][j], add[1]);
        v0.z = fmaf(mult[2], acc[2][j], add[2]);
        v0.w = fmaf(mult[3], acc[3][j], add[3]);
        v1.x = fmaf(mult[4], acc[4][j], add[4]);
        v1.y = fmaf(mult[5], acc[5][j], add[5]);
        v1.z = fmaf(mult[6], acc[6][j], add[6]);
        v1.w = fmaf(mult[7], acc[7][j], add[7]);
        if (isu){
            if constexpr (UB16){
                union { unsigned short u[8]; uint4 v; } o;
                o.u[0] = f2bf(v0.x); o.u[1] = f2bf(v0.y); o.u[2] = f2bf(v0.z); o.u[3] = f2bf(v0.w);
                o.u[4] = f2bf(v1.x); o.u[5] = f2bf(v1.y); o.u[6] = f2bf(v1.z); o.u[7] = f2bf(v1.w);
                *(uint4*)((unsigned short*)ub + (size_t)pt*O + mbase) = o.v;
            } else {
                float* d = ub + (size_t)pt*O + mbase;
                *(float4*)(d)     = v0;
                *(float4*)(d + 4) = v1;
            }
        } else {
            float* d = xcv + (size_t)pt*512 + (mbase - O);
            *(float4*)(d)     = v0;
            *(float4*)(d + 4) = v1;
        }
    }
}

// ---------------------------------------------------------------- layer-1 u/v (C=3) direct (fp32 u)
__global__ __launch_bounds__(256) void k_uv3(const float* __restrict__ xt,
    const float* __restrict__ wp,
    const float* __restrict__ g, const float* __restrict__ bp,
    const float* __restrict__ mp, const float* __restrict__ vp,
    float* __restrict__ ub, float* __restrict__ xcv)
{
    __shared__ float wpl[128*3];
    __shared__ float mult[128], add[128];
    const int tid = threadIdx.x;
    if (tid < 128){
        int m = tid;
        if (m < 64){
            float s = g[m] / sqrtf(vp[m] + EPSF);
            mult[m] = (s >= 0.f) ? 1.f : -1.f;
            add[m]  = 0.f;
        } else {
            int o = m - 64;
            float s = g[o] / sqrtf(vp[o] + EPSF);
            mult[m] = s;
            add[m]  = bp[o] - mp[o]*s;
        }
    }
    for (int i = tid; i < 128*3; i += 256) wpl[i] = wp[i];
    __syncthreads();

    const int ptl = tid >> 5, mg = tid & 31;
    const int m0 = mg * 4;
    const int pt = blockIdx.x*8 + ptl;
    float x0 = xt[pt*3+0], x1 = xt[pt*3+1], x2 = xt[pt*3+2];
    float4 v4;
    float tmp[4];
    #pragma unroll
    for (int r = 0; r < 4; ++r){
        int m = m0 + r;
        float a = wpl[m*3+0]*x0 + wpl[m*3+1]*x1 + wpl[m*3+2]*x2;
        tmp[r] = fmaf(mult[m], a, add[m]);
    }
    v4.x = tmp[0]; v4.y = tmp[1]; v4.z = tmp[2]; v4.w = tmp[3];
    if (m0 < 64) *(float4*)(ub + (size_t)pt*64 + m0) = v4;
    else         *(float4*)(xcv + (size_t)pt*512 + (m0 - 64)) = v4;
}

// ---------------------------------------------------------------- combine: out = lrelu(|s| * max_k u'[j_k] + v')
template<int O, bool UB16>
__global__ __launch_bounds__(256) void k_edgemax(const float* __restrict__ ub,
    const int* __restrict__ idxg,
    const float* __restrict__ g, const float* __restrict__ vp,
    float* __restrict__ xcv)
{
    constexpr int TPP = O / 4;
    constexpr int PPB = 256 / TPP;
    const int tid = threadIdx.x;
    const int pt  = blockIdx.x*PPB + tid / TPP;
    const int oq  = (tid % TPP) * 4;
    const int bb  = pt & ~(NN-1);

    int nb[KK];
    #pragma unroll
    for (int k = 0; k < KK; ++k) nb[k] = idxg[pt*KK + k];

    float4 mx;
    if constexpr (UB16){
        const unsigned short* ubh = (const unsigned short*)ub;
        uint2 r0 = *(const uint2*)(ubh + (size_t)(bb + nb[0])*O + oq);
        mx.x = __uint_as_float(r0.x << 16);
        mx.y = __uint_as_float(r0.x & 0xffff0000u);
        mx.z = __uint_as_float(r0.y << 16);
        mx.w = __uint_as_float(r0.y & 0xffff0000u);
        #pragma unroll
        for (int k = 1; k < KK; ++k){
            uint2 r = *(const uint2*)(ubh + (size_t)(bb + nb[k])*O + oq);
            mx.x = fmaxf(mx.x, __uint_as_float(r.x << 16));
            mx.y = fmaxf(mx.y, __uint_as_float(r.x & 0xffff0000u));
            mx.z = fmaxf(mx.z, __uint_as_float(r.y << 16));
            mx.w = fmaxf(mx.w, __uint_as_float(r.y & 0xffff0000u));
        }
    } else {
        mx = *(const float4*)(ub + (size_t)(bb + nb[0])*O + oq);
        #pragma unroll
        for (int k = 1; k < KK; ++k){
            float4 u = *(const float4*)(ub + (size_t)(bb + nb[k])*O + oq);
            mx.x = fmaxf(mx.x, u.x); mx.y = fmaxf(mx.y, u.y);
            mx.z = fmaxf(mx.z, u.z); mx.w = fmaxf(mx.w, u.w);
        }
    }
    float4 gv = *(const float4*)(g + oq);
    float4 vv = *(const float4*)(vp + oq);
    float4 as;
    as.x = fabsf(gv.x / sqrtf(vv.x + EPSF));
    as.y = fabsf(gv.y / sqrtf(vv.y + EPSF));
    as.z = fabsf(gv.z / sqrtf(vv.z + EPSF));
    as.w = fabsf(gv.w / sqrtf(vv.w + EPSF));
    float* d = xcv + (size_t)pt*512 + oq;
    float4 vr = *(const float4*)(d);
    float4 y;
    y.x = lrelu(fmaf(as.x, mx.x, vr.x));
    y.y = lrelu(fmaf(as.y, mx.y, vr.y));
    y.z = lrelu(fmaf(as.z, mx.z, vr.z));
    y.w = lrelu(fmaf(as.w, mx.w, vr.w));
    *(float4*)(d) = y;
}

// ---------------------------------------------------------------- fp32 -> bf16 cast (8 elems/thread)
__global__ void k_castbf(const float* __restrict__ s, unsigned short* __restrict__ d, int n8)
{
    int i = blockIdx.x*256 + threadIdx.x;
    if (i >= n8) return;
    const float4* sp = (const float4*)s + (size_t)i*2;
    float4 a = sp[0], b = sp[1];
    union { unsigned short u[8]; uint4 v; } o;
    o.u[0] = f2bf(a.x); o.u[1] = f2bf(a.y); o.u[2] = f2bf(a.z); o.u[3] = f2bf(a.w);
    o.u[4] = f2bf(b.x); o.u[5] = f2bf(b.y); o.u[6] = f2bf(b.z); o.u[7] = f2bf(b.w);
    *((uint4*)d + i) = o.v;
}

// ---------------------------------------------------------------- conv5 bf16 MFMA GEMM + BN + LReLU + pool partials
__global__ __launch_bounds__(256) void k_conv5mfma(const unsigned short* __restrict__ xcb,
    const unsigned short* __restrict__ w5b,
    const float* __restrict__ g, const float* __restrict__ bp,
    const float* __restrict__ mp, const float* __restrict__ vp,
    float* __restrict__ pmax, float* __restrict__ psum)
{
    __shared__ __align__(16) short lA[128*32];
    __shared__ __align__(16) short lB[128*32];
    __shared__ float scl[128], adl[128];
    __shared__ float red[2][128][2];

    const int tid = threadIdx.x;
    const int lane = tid & 63, wave = tid >> 6;
    const int wm = wave >> 1, wn = wave & 1;
    const int b  = blockIdx.x >> 6;
    const int mt = (blockIdx.x >> 3) & 7;
    const int nt = blockIdx.x & 7;

    if (tid < 128){
        int o = mt*128 + tid;
        float s = g[o] / sqrtf(vp[o] + EPSF);
        scl[tid] = s;
        adl[tid] = bp[o] - mp[o]*s;
    }

    f32x4 acc[4][4];
    #pragma unroll
    for (int i = 0; i < 4; ++i)
        #pragma unroll
        for (int j = 0; j < 4; ++j) acc[i][j] = (f32x4){0.f,0.f,0.f,0.f};

    const unsigned short* gA = w5b + (size_t)(mt*128)*512;
    const unsigned short* gB = xcb + (size_t)(b*1024 + nt*128)*512;

    for (int ks = 0; ks < 16; ++ks){
        __syncthreads();
        #pragma unroll
        for (int p = 0; p < 2; ++p){
            int off = p*256 + tid;
            int row = off >> 2;
            int slot = off & 3;
            int ssl = slot ^ (row & 3);
            *(uint4*)(lA + row*32 + ssl*8) = *(const uint4*)(gA + (size_t)row*512 + ks*32 + slot*8);
            *(uint4*)(lB + row*32 + ssl*8) = *(const uint4*)(gB + (size_t)row*512 + ks*32 + slot*8);
        }
        __syncthreads();

        short8v afr[4], bfr[4];
        #pragma unroll
        for (int i = 0; i < 4; ++i){
            int row = wm*64 + i*16 + (lane & 15);
            int sl  = (lane >> 4) ^ (row & 3);
            afr[i] = *(const short8v*)(lA + row*32 + sl*8);
        }
        #pragma unroll
        for (int j = 0; j < 4; ++j){
            int row = wn*64 + j*16 + (lane & 15);
            int sl  = (lane >> 4) ^ (row & 3);
            bfr[j] = *(const short8v*)(lB + row*32 + sl*8);
        }
        #pragma unroll
        for (int i = 0; i < 4; ++i)
            #pragma unroll
            for (int j = 0; j < 4; ++j)
                acc[i][j] = __builtin_amdgcn_mfma_f32_16x16x32_bf16(afr[i], bfr[j], acc[i][j], 0, 0, 0);
    }

    float emx[4][4], esm[4][4];
    #pragma unroll
    for (int i = 0; i < 4; ++i){
        #pragma unroll
        for (int r = 0; r < 4; ++r){
            int m_loc = wm*64 + i*16 + (lane >> 4)*4 + r;
            float s = scl[m_loc], t = adl[m_loc];
            float mx = NEGINF, sm = 0.f;
            #pragma unroll
            for (int j = 0; j < 4; ++j){
                float y = lrelu(fmaf(acc[i][j][r], s, t));
                mx = fmaxf(mx, y); sm += y;
            }
            #pragma unroll
            for (int d = 1; d < 16; d <<= 1){
                mx = fmaxf(mx, __shfl_xor(mx, d));
                sm += __shfl_xor(sm, d);
            }
            emx[i][r] = mx; esm[i][r] = sm;
        }
    }
    if ((lane & 15) == 0){
        #pragma unroll
        for (int i = 0; i < 4; ++i)
            #pragma unroll
            for (int r = 0; r < 4; ++r){
                int m_loc = wm*64 + i*16 + (lane >> 4)*4 + r;
                red[wn][m_loc][0] = emx[i][r];
                red[wn][m_loc][1] = esm[i][r];
            }
    }
    __syncthreads();
    if (tid < 128){
        float mx = fmaxf(red[0][tid][0], red[1][tid][0]);
        float sm = red[0][tid][1] + red[1][tid][1];
        int o = mt*128 + tid;
        pmax[(size_t)(b*NN + o)*8 + nt] = mx;
        psum[(size_t)(b*NN + o)*8 + nt] = sm;
    }
}

__global__ void k_poolfin(const float* __restrict__ pmax, const float* __restrict__ psum,
                          float* __restrict__ p)
{
    int i = blockIdx.x*256 + threadIdx.x;
    if (i >= NPT) return;
    int b = i >> 10, o = i & 1023;
    float mx = NEGINF, sm = 0.f;
    #pragma unroll
    for (int t = 0; t < 8; ++t){ mx = fmaxf(mx, pmax[(size_t)i*8 + t]); sm += psum[(size_t)i*8 + t]; }
    p[b*2048 + o]        = mx;
    p[b*2048 + 1024 + o] = sm * (1.f/1024.f);
}

// ---------------------------------------------------------------- small FC layers
template<int IN, int O, bool HASBN, bool HASBIAS>
__global__ void k_fc(const float* __restrict__ in, const float* __restrict__ W,
                     const float* __restrict__ bias,
                     const float* __restrict__ g, const float* __restrict__ bp,
                     const float* __restrict__ mp, const float* __restrict__ vp,
                     float* __restrict__ out)
{
    int i = blockIdx.x*256 + threadIdx.x;
    if (i >= BB*O) return;
    int b = i / O, o = i % O;
    const float* wr = W  + (size_t)o*IN;
    const float* ir = in + (size_t)b*IN;
    float s = 0.f;
    #pragma unroll 4
    for (int c = 0; c < IN; c += 4){
        float4 a = *(const float4*)(wr + c);
        float4 x = *(const float4*)(ir + c);
        s += dot4(a, x);
    }
    if (HASBIAS) s += bias[o];
    if (HASBN){
        float sc = g[o] / sqrtf(vp[o] + EPSF);
        s = (s - mp[o])*sc + bp[o];
        s = lrelu(s);
    }
    out[(size_t)b*O + o] = s;
}

// ---------------------------------------------------------------- launch
extern "C" void kernel_launch(void* const* d_in, const int* in_sizes, int n_in,
                              void* d_out, int out_size, void* d_ws, size_t ws_size,
                              hipStream_t stream)
{
    (void)in_sizes; (void)n_in; (void)out_size; (void)ws_size;
    const float* x   = (const float*)d_in[0];
    const float* w1  = (const float*)d_in[1];
    const float* w2  = (const float*)d_in[2];
    const float* w3  = (const float*)d_in[3];
    const float* w4  = (const float*)d_in[4];
    const float* w5  = (const float*)d_in[5];
    const float* wl1 = (const float*)d_in[6];
    const float* wl2 = (const float*)d_in[7];
    const float* wl3 = (const float*)d_in[8];
    const float* bl2 = (const float*)d_in[9];
    const float* bl3 = (const float*)d_in[10];
    const float* g1 = (const float*)d_in[11]; const float* b1 = (const float*)d_in[12];
    const float* m1 = (const float*)d_in[13]; const float* v1 = (const float*)d_in[14];
    const float* g2 = (const float*)d_in[15]; const float* b2 = (const float*)d_in[16];
    const float* m2 = (const float*)d_in[17]; const float* v2 = (const float*)d_in[18];
    const float* g3 = (const float*)d_in[19]; const float* b3 = (const float*)d_in[20];
    const float* m3 = (const float*)d_in[21]; const float* v3 = (const float*)d_in[22];
    const float* g4 = (const float*)d_in[23]; const float* b4 = (const float*)d_in[24];
    const float* m4 = (const float*)d_in[25]; const float* v4 = (const float*)d_in[26];
    const float* g5 = (const float*)d_in[27]; const float* b5 = (const float*)d_in[28];
    const float* m5 = (const float*)d_in[29]; const float* v5 = (const float*)d_in[30];
    const float* g6 = (const float*)d_in[31]; const float* b6 = (const float*)d_in[32];
    const float* m6 = (const float*)d_in[33]; const float* v6 = (const float*)d_in[34];
    const float* g7 = (const float*)d_in[35]; const float* b7 = (const float*)d_in[36];
    const float* m7 = (const float*)d_in[37]; const float* v7 = (const float*)d_in[38];

    float* wsf  = (float*)d_ws;
    float* xt0  = wsf;                    // 49152
    float* xc   = xt0 + 49152;            // 8388608
    float* xx   = xc + 8388608;           // 16384
    int*   idx  = (int*)(xx + 16384);     // 327680 ints
    float* pmax = (float*)(idx + 327680); // 131072
    float* psum = pmax + 131072;          // 131072
    float* p    = psum + 131072;          // 32768
    float* h1   = p + 32768;              // 8192
    float* h2   = h1 + 8192;              // 4096
    float* ub   = h2 + 4096;              // 4194304
    float* wp   = ub + 4194304;           // 65536
    unsigned short* xcb = (unsigned short*)ub;   // bf16 alias (ub dead by conv5)
    unsigned short* w5b = (unsigned short*)idx;  // bf16 alias (idx dead by conv5)

    k_transpose<<<64, 256, 0, stream>>>(x, xt0);

    // block 1: C=3 -> O=64 (channels 0..63)
    k_sqnorm<<<64, 256, 0, stream>>>(xt0, 3, 3, xx);
    k_knn<3><<<256, 1024, 0, stream>>>(xt0, 3, xx, idx);
    k_wprep<<<1, 256, 0, stream>>>(w1, 64, 3, wp);
    k_uv3<<<2048, 256, 0, stream>>>(xt0, wp, g1, b1, m1, v1, ub, xc);
    k_edgemax<64, false><<<1024, 256, 0, stream>>>(ub, idx, g1, v1, xc);

    // block 2: C=64 -> O=64 (channels 64..127)
    k_sqnorm<<<64, 256, 0, stream>>>(xc, 512, 64, xx);
    k_knn<64><<<256, 1024, 0, stream>>>(xc, 512, xx, idx);
    k_wprep<<<16, 256, 0, stream>>>(w2, 64, 64, wp);
    k_uvgemm<64, 128, 64, false><<<128, 256, 0, stream>>>(xc, wp, g2, b2, m2, v2, ub, xc + 64);
    k_edgemax<64, false><<<1024, 256, 0, stream>>>(ub, idx, g2, v2, xc + 64);

    // block 3: C=64 -> O=128 (channels 128..255)
    k_sqnorm<<<64, 256, 0, stream>>>(xc + 64, 512, 64, xx);
    k_knn<64><<<256, 1024, 0, stream>>>(xc + 64, 512, xx, idx);
    k_wprep<<<32, 256, 0, stream>>>(w3, 128, 64, wp);
    k_uvgemm<64, 256, 128, false><<<256, 256, 0, stream>>>(xc + 64, wp, g3, b3, m3, v3, ub, xc + 128);
    k_edgemax<128, false><<<2048, 256, 0, stream>>>(ub, idx, g3, v3, xc + 128);

    // block 4: C=128 -> O=256 (channels 256..511); u-table stored bf16
    k_sqnorm<<<64, 256, 0, stream>>>(xc + 128, 512, 128, xx);
    k_knn<128><<<256, 1024, 0, stream>>>(xc + 128, 512, xx, idx);
    k_wprep<<<128, 256, 0, stream>>>(w4, 256, 128, wp);
    k_uvgemm<128, 512, 256, true><<<512, 256, 0, stream>>>(xc + 128, wp, g4, b4, m4, v4, ub, xc + 256);
    k_edgemax<256, true><<<4096, 256, 0, stream>>>(ub, idx, g4, v4, xc + 256);

    // conv5: cast to bf16 (ub/idx now dead), MFMA GEMM + fused BN/LReLU/pool
    k_castbf<<<4096, 256, 0, stream>>>(xc, xcb, 1048576);
    k_castbf<<<256, 256, 0, stream>>>(w5, w5b, 65536);
    k_conv5mfma<<<1024, 256, 0, stream>>>(xcb, w5b, g5, b5, m5, v5, pmax, psum);
    k_poolfin<<<64, 256, 0, stream>>>(pmax, psum, p);

    // FC head
    k_fc<2048, 512, true,  false><<<32, 256, 0, stream>>>(p,  wl1, nullptr, g6, b6, m6, v6, h1);
    k_fc<512,  256, true,  true ><<<16, 256, 0, stream>>>(h1, wl2, bl2,     g7, b7, m7, v7, h2);
    k_fc<256,  101, false, true ><<<7,  256, 0, stream>>>(h2, wl3, bl3, nullptr, nullptr, nullptr, nullptr, (float*)d_out);
}

// Round 13
// 581.656 us; speedup vs baseline: 1.1684x; 1.0651x over previous
//
#include <hip/hip_runtime.h>
#include <cstdint>
#include <cmath>

#define DI __device__ __forceinline__

constexpr int BB = 16;      // batch
constexpr int NN = 1024;    // points
constexpr int KK = 20;      // neighbors
constexpr int NPT = BB*NN;  // total points 16384
constexpr float EPSF = 1e-5f;
constexpr float NEGINF = -3.0e38f;

DI float lrelu(float x){ return x >= 0.f ? x : 0.2f * x; }
DI float dot4(const float4 a, const float4 b){ return a.x*b.x + a.y*b.y + a.z*b.z + a.w*b.w; }
DI unsigned short f2bf(float x){            // round-to-nearest-even bf16
    uint32_t u = __float_as_uint(x);
    uint32_t r = (u + 0x7fffu + ((u >> 16) & 1u)) >> 16;
    return (unsigned short)r;
}

// wave64 max: 4 DPP row-rotate steps (VALU pipe) + 2 cross-row shuffles.
// Rotations {1,2,4,8} within each 16-lane row form a complete log-reduce
// (subset sums cover offsets 0..15), then xor16/xor32 combine rows.
DI float wave_max64(float v){
    v = fmaxf(v, __int_as_float(__builtin_amdgcn_mov_dpp(__float_as_int(v), 0x121, 0xF, 0xF, true)));
    v = fmaxf(v, __int_as_float(__builtin_amdgcn_mov_dpp(__float_as_int(v), 0x122, 0xF, 0xF, true)));
    v = fmaxf(v, __int_as_float(__builtin_amdgcn_mov_dpp(__float_as_int(v), 0x124, 0xF, 0xF, true)));
    v = fmaxf(v, __int_as_float(__builtin_amdgcn_mov_dpp(__float_as_int(v), 0x128, 0xF, 0xF, true)));
    v = fmaxf(v, __shfl_xor(v, 16));
    v = fmaxf(v, __shfl_xor(v, 32));
    return v;
}

typedef __attribute__((ext_vector_type(8))) short short8v;  // bf16x8 MFMA fragment
typedef __attribute__((ext_vector_type(4))) float f32x4;

// ---------------------------------------------------------------- transpose x [B,3,N] -> xt0 [B,N,3]
__global__ void k_transpose(const float* __restrict__ x, float* __restrict__ xt)
{
    int i = blockIdx.x * 256 + threadIdx.x;
    if (i >= NPT) return;
    int b = i >> 10, n = i & 1023;
    #pragma unroll
    for (int c = 0; c < 3; ++c) xt[i*3 + c] = x[(b*3 + c)*NN + n];
}

// ---------------------------------------------------------------- squared norms per point
__global__ void k_sqnorm(const float* __restrict__ src, int stride, int C, float* __restrict__ xx)
{
    int i = blockIdx.x * 256 + threadIdx.x;
    if (i >= NPT) return;
    const float* r = src + (size_t)i * stride;
    float s = 0.f;
    for (int c = 0; c < C; ++c){ float v = r[c]; s += v * v; }
    xx[i] = s;
}

// ---------------------------------------------------------------- kNN
// Block = 1024 threads (16 waves), 64 queries (wave -> 4 queries), grid 256.
// C>3: DOUBLE-BUFFERED candidate tiles (1 barrier/tile; next tile's global
// loads issue right after the barrier and stay in flight under the compute;
// ds_write's register dependency provides the wait). Queries: wave-uniform
// global (scalar) loads. Selection: per-lane bitonic sort + 21-round
// tournament with DPP-accelerated wave-max, then set emission (R8 semantics).
template<int C>
__global__ __launch_bounds__(1024, 4) void k_knn(const float* __restrict__ src, int stride,
                                                 const float* __restrict__ xx,
                                                 int* __restrict__ idxo)
{
    constexpr bool SMALL = (C == 3);
    constexpr int CG = SMALL ? 1 : (C / 4);
    constexpr int TS = SMALL ? 5 : C;
    constexpr int NBUF = SMALL ? 1 : 2;
    constexpr int LPT = SMALL ? 1 : (128*CG/1024);   // float4 chunks per thread
    __shared__ float tile[NBUF][128 * TS];

    const int tid  = threadIdx.x;
    const int lane = tid & 63;
    const int wv   = __builtin_amdgcn_readfirstlane(tid >> 6);  // 0..15 uniform
    const int b  = blockIdx.x >> 4;
    const int q0 = (blockIdx.x & 15) << 6;
    const int qbase = b*NN + q0 + (wv << 2);      // wave's first query (uniform)

    const float* qp0 = src + (size_t)(qbase + 0)*stride;
    const float* qp1 = src + (size_t)(qbase + 1)*stride;
    const float* qp2 = src + (size_t)(qbase + 2)*stride;
    const float* qp3 = src + (size_t)(qbase + 3)*stride;

    float xxq[4];
    #pragma unroll
    for (int q = 0; q < 4; ++q) xxq[q] = xx[qbase + q];

    float val[4][16];

    if constexpr (SMALL){
        #pragma unroll
        for (int t = 0; t < 8; ++t){
            __syncthreads();
            for (int i = tid; i < 128*3; i += 1024){
                int row = i / 3, c = i % 3;
                tile[0][row*TS + c] = src[(size_t)(b*NN + t*128 + row)*stride + c];
            }
            __syncthreads();
            float c0a = tile[0][lane*TS+0], c0b = tile[0][lane*TS+1], c0c = tile[0][lane*TS+2];
            float c1a = tile[0][(64+lane)*TS+0], c1b = tile[0][(64+lane)*TS+1], c1c = tile[0][(64+lane)*TS+2];
            float q00 = qp0[0], q01 = qp0[1], q02 = qp0[2];
            float q10 = qp1[0], q11 = qp1[1], q12 = qp1[2];
            float q20 = qp2[0], q21 = qp2[1], q22 = qp2[2];
            float q30 = qp3[0], q31 = qp3[1], q32 = qp3[2];
            float xxm0 = xx[b*NN + t*128 + lane];
            float xxm1 = xx[b*NN + t*128 + 64 + lane];
            val[0][2*t]   = 2.f*(q00*c0a + q01*c0b + q02*c0c) - xxq[0] - xxm0;
            val[0][2*t+1] = 2.f*(q00*c1a + q01*c1b + q02*c1c) - xxq[0] - xxm1;
            val[1][2*t]   = 2.f*(q10*c0a + q11*c0b + q12*c0c) - xxq[1] - xxm0;
            val[1][2*t+1] = 2.f*(q10*c1a + q11*c1b + q12*c1c) - xxq[1] - xxm1;
            val[2][2*t]   = 2.f*(q20*c0a + q21*c0b + q22*c0c) - xxq[2] - xxm0;
            val[2][2*t+1] = 2.f*(q20*c1a + q21*c1b + q22*c1c) - xxq[2] - xxm1;
            val[3][2*t]   = 2.f*(q30*c0a + q31*c0b + q32*c0c) - xxq[3] - xxm0;
            val[3][2*t+1] = 2.f*(q30*c1a + q31*c1b + q32*c1c) - xxq[3] - xxm1;
        }
    } else {
        // ---- prologue: stage tile 0 ----
        float4 nx[LPT];
        #pragma unroll
        for (int k = 0; k < LPT; ++k){
            int i = tid + k*1024;
            int row = i / CG, cg = i % CG;
            nx[k] = *(const float4*)(src + (size_t)(b*NN + row)*stride + cg*4);
        }
        #pragma unroll
        for (int k = 0; k < LPT; ++k){
            int i = tid + k*1024;
            int row = i / CG, cg = i % CG;
            int p = cg ^ (row & (CG - 1));
            *(float4*)(&tile[0][row*TS + p*4]) = nx[k];
        }

        for (int t = 0; t < 8; ++t){
            __syncthreads();                       // tile t's ds_writes visible
            if (t < 7){
                #pragma unroll
                for (int k = 0; k < LPT; ++k){     // issue next tile's loads (in flight under compute)
                    int i = tid + k*1024;
                    int row = i / CG, cg = i % CG;
                    nx[k] = *(const float4*)(src + (size_t)(b*NN + (t+1)*128 + row)*stride + cg*4);
                }
            }
            const float* tb = tile[t & 1];

            float acc[4][2];
            #pragma unroll
            for (int q = 0; q < 4; ++q){ acc[q][0] = 0.f; acc[q][1] = 0.f; }
            const int sw = lane & (CG - 1);
            #pragma unroll 2
            for (int cg0 = 0; cg0 < CG; ++cg0){
                float4 cf0 = *(const float4*)(tb + lane*TS      + ((cg0 ^ sw) << 2));
                float4 cf1 = *(const float4*)(tb + (64+lane)*TS + ((cg0 ^ sw) << 2));
                float4 qf0 = *(const float4*)(qp0 + (cg0 << 2));
                float4 qf1 = *(const float4*)(qp1 + (cg0 << 2));
                float4 qf2 = *(const float4*)(qp2 + (cg0 << 2));
                float4 qf3 = *(const float4*)(qp3 + (cg0 << 2));
                acc[0][0] += dot4(qf0, cf0); acc[0][1] += dot4(qf0, cf1);
                acc[1][0] += dot4(qf1, cf0); acc[1][1] += dot4(qf1, cf1);
                acc[2][0] += dot4(qf2, cf0); acc[2][1] += dot4(qf2, cf1);
                acc[3][0] += dot4(qf3, cf0); acc[3][1] += dot4(qf3, cf1);
            }
            float xxm0 = xx[b*NN + t*128 + lane];
            float xxm1 = xx[b*NN + t*128 + 64 + lane];
            #pragma unroll
            for (int q = 0; q < 4; ++q){
                val[q][2*t]   = 2.f*acc[q][0] - xxq[q] - xxm0;
                val[q][2*t+1] = 2.f*acc[q][1] - xxq[q] - xxm1;
            }

            if (t < 7){
                float* wb = &tile[(t+1) & 1][0];   // write-after-read safe: see barrier argument
                #pragma unroll
                for (int k = 0; k < LPT; ++k){
                    int i = tid + k*1024;
                    int row = i / CG, cg = i % CG;
                    int p = cg ^ (row & (CG - 1));
                    *(float4*)(&wb[row*TS + p*4]) = nx[k];
                }
            }
        }
    }

    // ---- selection per query: bitonic sort + DPP tournament (R8 semantics) ----
    #pragma unroll
    for (int q = 0; q < 4; ++q){
        const int orow = (qbase + q) * KK;

        float s[16];
        #pragma unroll
        for (int j = 0; j < 16; ++j) s[j] = val[q][j];
        #pragma unroll
        for (int k = 2; k <= 16; k <<= 1){
            #pragma unroll
            for (int jj = k >> 1; jj > 0; jj >>= 1){
                #pragma unroll
                for (int i = 0; i < 16; ++i){
                    int l = i ^ jj;
                    if (l > i){
                        float a = s[i], c = s[l];
                        float mx = fmaxf(a, c), mn = fminf(a, c);
                        bool up = ((i & k) == 0);
                        s[i] = up ? mx : mn;
                        s[l] = up ? mn : mx;
                    }
                }
            }
        }

        float T = NEGINF;
        for (int it = 0; it < 21; ++it){
            float m = wave_max64(s[0]);
            T = m;
            unsigned long long mk = __ballot(s[0] == m);
            int wl = __ffsll(mk) - 1;
            bool adv = (lane == wl);
            #pragma unroll
            for (int j = 0; j < 15; ++j) s[j] = adv ? s[j+1] : s[j];
            s[15] = adv ? NEGINF : s[15];
        }

        int cnt = 0;
        #pragma unroll
        for (int j = 0; j < 16; ++j) cnt += (val[q][j] > T) ? 1 : 0;
        int off = cnt;
        #pragma unroll
        for (int d = 1; d < 64; d <<= 1){
            int tt = __shfl_up(off, d);
            if (lane >= d) off += tt;
        }
        int total = __shfl(off, 63);
        int pos = orow + off - cnt;
        #pragma unroll
        for (int j = 0; j < 16; ++j){
            if (val[q][j] > T){ idxo[pos] = j*64 + lane; ++pos; }
        }
        if (total < KK){
            int rem = KK - total;
            int prior = 0;
            #pragma unroll
            for (int j = 0; j < 16; ++j){
                unsigned long long mk = __ballot(val[q][j] == T);
                int below = __popcll(mk & ((1ull << lane) - 1ull));
                if ((val[q][j] == T) && (prior + below < rem))
                    idxo[orow + total + prior + below] = j*64 + lane;
                prior += __popcll(mk);
            }
        }
    }
}

// ---------------------------------------------------------------- weight prep: W' = [Wj ; Wi-Wj]
__global__ void k_wprep(const float* __restrict__ w, int O, int C, float* __restrict__ wp)
{
    int i = blockIdx.x*256 + threadIdx.x;
    if (i >= O*C) return;
    int o = i / C, c = i % C;
    float a = w[o*2*C + c];
    float bq = w[o*2*C + C + c];
    wp[o*C + c]       = a;
    wp[(O + o)*C + c] = bq - a;
}

// ---------------------------------------------------------------- u/v GEMM (fp32 math; u-rows optionally stored bf16)
template<int K, int M2, int O, bool UB16>
__global__ __launch_bounds__(256) void k_uvgemm(const float* __restrict__ srcp,
    const float* __restrict__ wp,
    const float* __restrict__ g, const float* __restrict__ bp,
    const float* __restrict__ mp, const float* __restrict__ vp,
    float* __restrict__ ub, float* __restrict__ xcv)
{
    constexpr int LD = 136;
    __shared__ float wl[16*LD];
    __shared__ float xl[16*LD];
    const int tid = threadIdx.x;
    const int nt = blockIdx.x & 127;
    const int mt = blockIdx.x >> 7;
    const int to = tid >> 4, tn = tid & 15;

    float acc[8][8];
    #pragma unroll
    for (int i = 0; i < 8; ++i)
        #pragma unroll
        for (int j = 0; j < 8; ++j) acc[i][j] = 0.f;

    for (int c0 = 0; c0 < K; c0 += 16){
        __syncthreads();
        #pragma unroll
        for (int p = 0; p < 2; ++p){
            int fi = tid + (p << 8);
            int row = fi >> 2, cq = (fi & 3) << 2;
            float4 wv = *(const float4*)(wp + (size_t)(mt*128 + row)*K + c0 + cq);
            wl[(cq+0)*LD + row] = wv.x;
            wl[(cq+1)*LD + row] = wv.y;
            wl[(cq+2)*LD + row] = wv.z;
            wl[(cq+3)*LD + row] = wv.w;
            float4 xv = *(const float4*)(srcp + (size_t)(nt*128 + row)*512 + c0 + cq);
            xl[(cq+0)*LD + row] = xv.x;
            xl[(cq+1)*LD + row] = xv.y;
            xl[(cq+2)*LD + row] = xv.z;
            xl[(cq+3)*LD + row] = xv.w;
        }
        __syncthreads();
        #pragma unroll
        for (int cc = 0; cc < 16; ++cc){
            float4 a0 = *(const float4*)(wl + cc*LD + to*8);
            float4 a1 = *(const float4*)(wl + cc*LD + to*8 + 4);
            float4 b0 = *(const float4*)(xl + cc*LD + tn*8);
            float4 b1 = *(const float4*)(xl + cc*LD + tn*8 + 4);
            float av[8] = {a0.x,a0.y,a0.z,a0.w,a1.x,a1.y,a1.z,a1.w};
            float bv[8] = {b0.x,b0.y,b0.z,b0.w,b1.x,b1.y,b1.z,b1.w};
            #pragma unroll
            for (int i = 0; i < 8; ++i)
                #pragma unroll
                for (int j = 0; j < 8; ++j) acc[i][j] += av[i]*bv[j];
        }
    }

    const int mbase = mt*128 + to*8;
    const bool isu = mbase < O;
    float mult[8], add[8];
    #pragma unroll
    for (int i = 0; i < 8; ++i){
        int m = mbase + i;
        if (isu){
            float s = g[m] / sqrtf(vp[m] + EPSF);
            mult[i] = (s >= 0.f) ? 1.f : -1.f;
            add[i]  = 0.f;
        } else {
            int o = m - O;
            float s = g[o] / sqrtf(vp[o] + EPSF);
            mult[i] = s;
            add[i]  = bp[o] - mp[o]*s;
        }
    }
    #pragma unroll
    for (int j = 0; j < 8; ++j){
        int pt = nt*128 + tn*8 + j;
        float4 v0, v1;
        v0.x = fmaf(mult[0], acc[0][j], add[0]);
        v0.y = fmaf(mult[1], acc[1][j], add[1]);
        v0.z = fmaf(mult[2], acc[2][j], add[2]);
        v0.w = fmaf(mult[3], acc[3][j], add[3]);
        v1.x = fmaf(mult[4], acc[4][j], add[4]);
        v1.y = fmaf(mult[5], acc[5][j], add[5]);
        v1.z = fmaf(mult[6], acc[6][j], add[6]);
        v1.w = fmaf(mult[7], acc[7][j], add[7]);
        if (isu){
            if constexpr (UB16){
                union { unsigned short u[8]; uint4 v; } o;
                o.u[0] = f2bf(v0.x); o.u[1] = f2bf(v0.y); o.u[2] = f2bf(v0.z); o.u[3] = f2bf(v0.w);
                o.u[4] = f2bf(v1.x); o.u[5] = f2bf(v1.y); o.u[6] = f2bf(v1.z); o.u[7] = f2bf(v1.w);
                *(uint4*)((unsigned short*)ub + (size_t)pt*O + mbase) = o.v;
            } else {
                float* d = ub + (size_t)pt*O + mbase;
                *(float4*)(d)     = v0;
                *(float4*)(d + 4) = v1;
            }
        } else {
            float* d = xcv + (size_t)pt*512 + (mbase - O);
            *(float4*)(d)     = v0;
            *(float4*)(d + 4) = v1;
        }
    }
}

// ---------------------------------------------------------------- layer-1 u/v (C=3) direct (fp32 u)
__global__ __launch_bounds__(256) void k_uv3(const float* __restrict__ xt,
    const float* __restrict__ wp,
    const float* __restrict__ g, const float* __restrict__ bp,
    const float* __restrict__ mp, const float* __restrict__ vp,
    float* __restrict__ ub, float* __restrict__ xcv)
{
    __shared__ float wpl[128*3];
    __shared__ float mult[128], add[128];
    const int tid = threadIdx.x;
    if (tid < 128){
        int m = tid;
        if (m < 64){
            float s = g[m] / sqrtf(vp[m] + EPSF);
            mult[m] = (s >= 0.f) ? 1.f : -1.f;
            add[m]  = 0.f;
        } else {
            int o = m - 64;
            float s = g[o] / sqrtf(vp[o] + EPSF);
            mult[m] = s;
            add[m]  = bp[o] - mp[o]*s;
        }
    }
    for (int i = tid; i < 128*3; i += 256) wpl[i] = wp[i];
    __syncthreads();

    const int ptl = tid >> 5, mg = tid & 31;
    const int m0 = mg * 4;
    const int pt = blockIdx.x*8 + ptl;
    float x0 = xt[pt*3+0], x1 = xt[pt*3+1], x2 = xt[pt*3+2];
    float4 v4;
    float tmp[4];
    #pragma unroll
    for (int r = 0; r < 4; ++r){
        int m = m0 + r;
        float a = wpl[m*3+0]*x0 + wpl[m*3+1]*x1 + wpl[m*3+2]*x2;
        tmp[r] = fmaf(mult[m], a, add[m]);
    }
    v4.x = tmp[0]; v4.y = tmp[1]; v4.z = tmp[2]; v4.w = tmp[3];
    if (m0 < 64) *(float4*)(ub + (size_t)pt*64 + m0) = v4;
    else         *(float4*)(xcv + (size_t)pt*512 + (m0 - 64)) = v4;
}

// ---------------------------------------------------------------- combine: out = lrelu(|s| * max_k u'[j_k] + v')
template<int O, bool UB16>
__global__ __launch_bounds__(256) void k_edgemax(const float* __restrict__ ub,
    const int* __restrict__ idxg,
    const float* __restrict__ g, const float* __restrict__ vp,
    float* __restrict__ xcv)
{
    constexpr int TPP = O / 4;
    constexpr int PPB = 256 / TPP;
    const int tid = threadIdx.x;
    const int pt  = blockIdx.x*PPB + tid / TPP;
    const int oq  = (tid % TPP) * 4;
    const int bb  = pt & ~(NN-1);

    int nb[KK];
    #pragma unroll
    for (int k = 0; k < KK; ++k) nb[k] = idxg[pt*KK + k];

    float4 mx;
    if constexpr (UB16){
        const unsigned short* ubh = (const unsigned short*)ub;
        uint2 r0 = *(const uint2*)(ubh + (size_t)(bb + nb[0])*O + oq);
        mx.x = __uint_as_float(r0.x << 16);
        mx.y = __uint_as_float(r0.x & 0xffff0000u);
        mx.z = __uint_as_float(r0.y << 16);
        mx.w = __uint_as_float(r0.y & 0xffff0000u);
        #pragma unroll
        for (int k = 1; k < KK; ++k){
            uint2 r = *(const uint2*)(ubh + (size_t)(bb + nb[k])*O + oq);
            mx.x = fmaxf(mx.x, __uint_as_float(r.x << 16));
            mx.y = fmaxf(mx.y, __uint_as_float(r.x & 0xffff0000u));
            mx.z = fmaxf(mx.z, __uint_as_float(r.y << 16));
            mx.w = fmaxf(mx.w, __uint_as_float(r.y & 0xffff0000u));
        }
    } else {
        mx = *(const float4*)(ub + (size_t)(bb + nb[0])*O + oq);
        #pragma unroll
        for (int k = 1; k < KK; ++k){
            float4 u = *(const float4*)(ub + (size_t)(bb + nb[k])*O + oq);
            mx.x = fmaxf(mx.x, u.x); mx.y = fmaxf(mx.y, u.y);
            mx.z = fmaxf(mx.z, u.z); mx.w = fmaxf(mx.w, u.w);
        }
    }
    float4 gv = *(const float4*)(g + oq);
    float4 vv = *(const float4*)(vp + oq);
    float4 as;
    as.x = fabsf(gv.x / sqrtf(vv.x + EPSF));
    as.y = fabsf(gv.y / sqrtf(vv.y + EPSF));
    as.z = fabsf(gv.z / sqrtf(vv.z + EPSF));
    as.w = fabsf(gv.w / sqrtf(vv.w + EPSF));
    float* d = xcv + (size_t)pt*512 + oq;
    float4 vr = *(const float4*)(d);
    float4 y;
    y.x = lrelu(fmaf(as.x, mx.x, vr.x));
    y.y = lrelu(fmaf(as.y, mx.y, vr.y));
    y.z = lrelu(fmaf(as.z, mx.z, vr.z));
    y.w = lrelu(fmaf(as.w, mx.w, vr.w));
    *(float4*)(d) = y;
}

// ---------------------------------------------------------------- fp32 -> bf16 cast (8 elems/thread)
__global__ void k_castbf(const float* __restrict__ s, unsigned short* __restrict__ d, int n8)
{
    int i = blockIdx.x*256 + threadIdx.x;
    if (i >= n8) return;
    const float4* sp = (const float4*)s + (size_t)i*2;
    float4 a = sp[0], b = sp[1];
    union { unsigned short u[8]; uint4 v; } o;
    o.u[0] = f2bf(a.x); o.u[1] = f2bf(a.y); o.u[2] = f2bf(a.z); o.u[3] = f2bf(a.w);
    o.u[4] = f2bf(b.x); o.u[5] = f2bf(b.y); o.u[6] = f2bf(b.z); o.u[7] = f2bf(b.w);
    *((uint4*)d + i) = o.v;
}

// ---------------------------------------------------------------- conv5 bf16 MFMA GEMM + BN + LReLU + pool partials
__global__ __launch_bounds__(256) void k_conv5mfma(const unsigned short* __restrict__ xcb,
    const unsigned short* __restrict__ w5b,
    const float* __restrict__ g, const float* __restrict__ bp,
    const float* __restrict__ mp, const float* __restrict__ vp,
    float* __restrict__ pmax, float* __restrict__ psum)
{
    __shared__ __align__(16) short lA[128*32];
    __shared__ __align__(16) short lB[128*32];
    __shared__ float scl[128], adl[128];
    __shared__ float red[2][128][2];

    const int tid = threadIdx.x;
    const int lane = tid & 63, wave = tid >> 6;
    const int wm = wave >> 1, wn = wave & 1;
    const int b  = blockIdx.x >> 6;
    const int mt = (blockIdx.x >> 3) & 7;
    const int nt = blockIdx.x & 7;

    if (tid < 128){
        int o = mt*128 + tid;
        float s = g[o] / sqrtf(vp[o] + EPSF);
        scl[tid] = s;
        adl[tid] = bp[o] - mp[o]*s;
    }

    f32x4 acc[4][4];
    #pragma unroll
    for (int i = 0; i < 4; ++i)
        #pragma unroll
        for (int j = 0; j < 4; ++j) acc[i][j] = (f32x4){0.f,0.f,0.f,0.f};

    const unsigned short* gA = w5b + (size_t)(mt*128)*512;
    const unsigned short* gB = xcb + (size_t)(b*1024 + nt*128)*512;

    for (int ks = 0; ks < 16; ++ks){
        __syncthreads();
        #pragma unroll
        for (int p = 0; p < 2; ++p){
            int off = p*256 + tid;
            int row = off >> 2;
            int slot = off & 3;
            int ssl = slot ^ (row & 3);
            *(uint4*)(lA + row*32 + ssl*8) = *(const uint4*)(gA + (size_t)row*512 + ks*32 + slot*8);
            *(uint4*)(lB + row*32 + ssl*8) = *(const uint4*)(gB + (size_t)row*512 + ks*32 + slot*8);
        }
        __syncthreads();

        short8v afr[4], bfr[4];
        #pragma unroll
        for (int i = 0; i < 4; ++i){
            int row = wm*64 + i*16 + (lane & 15);
            int sl  = (lane >> 4) ^ (row & 3);
            afr[i] = *(const short8v*)(lA + row*32 + sl*8);
        }
        #pragma unroll
        for (int j = 0; j < 4; ++j){
            int row = wn*64 + j*16 + (lane & 15);
            int sl  = (lane >> 4) ^ (row & 3);
            bfr[j] = *(const short8v*)(lB + row*32 + sl*8);
        }
        #pragma unroll
        for (int i = 0; i < 4; ++i)
            #pragma unroll
            for (int j = 0; j < 4; ++j)
                acc[i][j] = __builtin_amdgcn_mfma_f32_16x16x32_bf16(afr[i], bfr[j], acc[i][j], 0, 0, 0);
    }

    float emx[4][4], esm[4][4];
    #pragma unroll
    for (int i = 0; i < 4; ++i){
        #pragma unroll
        for (int r = 0; r < 4; ++r){
            int m_loc = wm*64 + i*16 + (lane >> 4)*4 + r;
            float s = scl[m_loc], t = adl[m_loc];
            float mx = NEGINF, sm = 0.f;
            #pragma unroll
            for (int j = 0; j < 4; ++j){
                float y = lrelu(fmaf(acc[i][j][r], s, t));
                mx = fmaxf(mx, y); sm += y;
            }
            #pragma unroll
            for (int d = 1; d < 16; d <<= 1){
                mx = fmaxf(mx, __shfl_xor(mx, d));
                sm += __shfl_xor(sm, d);
            }
            emx[i][r] = mx; esm[i][r] = sm;
        }
    }
    if ((lane & 15) == 0){
        #pragma unroll
        for (int i = 0; i < 4; ++i)
            #pragma unroll
            for (int r = 0; r < 4; ++r){
                int m_loc = wm*64 + i*16 + (lane >> 4)*4 + r;
                red[wn][m_loc][0] = emx[i][r];
                red[wn][m_loc][1] = esm[i][r];
            }
    }
    __syncthreads();
    if (tid < 128){
        float mx = fmaxf(red[0][tid][0], red[1][tid][0]);
        float sm = red[0][tid][1] + red[1][tid][1];
        int o = mt*128 + tid;
        pmax[(size_t)(b*NN + o)*8 + nt] = mx;
        psum[(size_t)(b*NN + o)*8 + nt] = sm;
    }
}

__global__ void k_poolfin(const float* __restrict__ pmax, const float* __restrict__ psum,
                          float* __restrict__ p)
{
    int i = blockIdx.x*256 + threadIdx.x;
    if (i >= NPT) return;
    int b = i >> 10, o = i & 1023;
    float mx = NEGINF, sm = 0.f;
    #pragma unroll
    for (int t = 0; t < 8; ++t){ mx = fmaxf(mx, pmax[(size_t)i*8 + t]); sm += psum[(size_t)i*8 + t]; }
    p[b*2048 + o]        = mx;
    p[b*2048 + 1024 + o] = sm * (1.f/1024.f);
}

// ---------------------------------------------------------------- small FC layers
template<int IN, int O, bool HASBN, bool HASBIAS>
__global__ void k_fc(const float* __restrict__ in, const float* __restrict__ W,
                     const float* __restrict__ bias,
                     const float* __restrict__ g, const float* __restrict__ bp,
                     const float* __restrict__ mp, const float* __restrict__ vp,
                     float* __restrict__ out)
{
    int i = blockIdx.x*256 + threadIdx.x;
    if (i >= BB*O) return;
    int b = i / O, o = i % O;
    const float* wr = W  + (size_t)o*IN;
    const float* ir = in + (size_t)b*IN;
    float s = 0.f;
    #pragma unroll 4
    for (int c = 0; c < IN; c += 4){
        float4 a = *(const float4*)(wr + c);
        float4 x = *(const float4*)(ir + c);
        s += dot4(a, x);
    }
    if (HASBIAS) s += bias[o];
    if (HASBN){
        float sc = g[o] / sqrtf(vp[o] + EPSF);
        s = (s - mp[o])*sc + bp[o];
        s = lrelu(s);
    }
    out[(size_t)b*O + o] = s;
}

// ---------------------------------------------------------------- launch
extern "C" void kernel_launch(void* const* d_in, const int* in_sizes, int n_in,
                              void* d_out, int out_size, void* d_ws, size_t ws_size,
                              hipStream_t stream)
{
    (void)in_sizes; (void)n_in; (void)out_size; (void)ws_size;
    const float* x   = (const float*)d_in[0];
    const float* w1  = (const float*)d_in[1];
    const float* w2  = (const float*)d_in[2];
    const float* w3  = (const float*)d_in[3];
    const float* w4  = (const float*)d_in[4];
    const float* w5  = (const float*)d_in[5];
    const float* wl1 = (const float*)d_in[6];
    const float* wl2 = (const float*)d_in[7];
    const float* wl3 = (const float*)d_in[8];
    const float* bl2 = (const float*)d_in[9];
    const float* bl3 = (const float*)d_in[10];
    const float* g1 = (const float*)d_in[11]; const float* b1 = (const float*)d_in[12];
    const float* m1 = (const float*)d_in[13]; const float* v1 = (const float*)d_in[14];
    const float* g2 = (const float*)d_in[15]; const float* b2 = (const float*)d_in[16];
    const float* m2 = (const float*)d_in[17]; const float* v2 = (const float*)d_in[18];
    const float* g3 = (const float*)d_in[19]; const float* b3 = (const float*)d_in[20];
    const float* m3 = (const float*)d_in[21]; const float* v3 = (const float*)d_in[22];
    const float* g4 = (const float*)d_in[23]; const float* b4 = (const float*)d_in[24];
    const float* m4 = (const float*)d_in[25]; const float* v4 = (const float*)d_in[26];
    const float* g5 = (const float*)d_in[27]; const float* b5 = (const float*)d_in[28];
    const float* m5 = (const float*)d_in[29]; const float* v5 = (const float*)d_in[30];
    const float* g6 = (const float*)d_in[31]; const float* b6 = (const float*)d_in[32];
    const float* m6 = (const float*)d_in[33]; const float* v6 = (const float*)d_in[34];
    const float* g7 = (const float*)d_in[35]; const float* b7 = (const float*)d_in[36];
    const float* m7 = (const float*)d_in[37]; const float* v7 = (const float*)d_in[38];

    float* wsf  = (float*)d_ws;
    float* xt0  = wsf;                    // 49152
    float* xc   = xt0 + 49152;            // 8388608
    float* xx   = xc + 8388608;           // 16384
    int*   idx  = (int*)(xx + 16384);     // 327680 ints
    float* pmax = (float*)(idx + 327680); // 131072
    float* psum = pmax + 131072;          // 131072
    float* p    = psum + 131072;          // 32768
    float* h1   = p + 32768;              // 8192
    float* h2   = h1 + 8192;              // 4096
    float* ub   = h2 + 4096;              // 4194304
    float* wp   = ub + 4194304;           // 65536
    unsigned short* xcb = (unsigned short*)ub;   // bf16 alias (ub dead by conv5)
    unsigned short* w5b = (unsigned short*)idx;  // bf16 alias (idx dead by conv5)

    k_transpose<<<64, 256, 0, stream>>>(x, xt0);

    // block 1: C=3 -> O=64 (channels 0..63)
    k_sqnorm<<<64, 256, 0, stream>>>(xt0, 3, 3, xx);
    k_knn<3><<<256, 1024, 0, stream>>>(xt0, 3, xx, idx);
    k_wprep<<<1, 256, 0, stream>>>(w1, 64, 3, wp);
    k_uv3<<<2048, 256, 0, stream>>>(xt0, wp, g1, b1, m1, v1, ub, xc);
    k_edgemax<64, false><<<1024, 256, 0, stream>>>(ub, idx, g1, v1, xc);

    // block 2: C=64 -> O=64 (channels 64..127)
    k_sqnorm<<<64, 256, 0, stream>>>(xc, 512, 64, xx);
    k_knn<64><<<256, 1024, 0, stream>>>(xc, 512, xx, idx);
    k_wprep<<<16, 256, 0, stream>>>(w2, 64, 64, wp);
    k_uvgemm<64, 128, 64, false><<<128, 256, 0, stream>>>(xc, wp, g2, b2, m2, v2, ub, xc + 64);
    k_edgemax<64, false><<<1024, 256, 0, stream>>>(ub, idx, g2, v2, xc + 64);

    // block 3: C=64 -> O=128 (channels 128..255)
    k_sqnorm<<<64, 256, 0, stream>>>(xc + 64, 512, 64, xx);
    k_knn<64><<<256, 1024, 0, stream>>>(xc + 64, 512, xx, idx);
    k_wprep<<<32, 256, 0, stream>>>(w3, 128, 64, wp);
    k_uvgemm<64, 256, 128, false><<<256, 256, 0, stream>>>(xc + 64, wp, g3, b3, m3, v3, ub, xc + 128);
    k_edgemax<128, false><<<2048, 256, 0, stream>>>(ub, idx, g3, v3, xc + 128);

    // block 4: C=128 -> O=256 (channels 256..511); u-table stored bf16
    k_sqnorm<<<64, 256, 0, stream>>>(xc + 128, 512, 128, xx);
    k_knn<128><<<256, 1024, 0, stream>>>(xc + 128, 512, xx, idx);
    k_wprep<<<128, 256, 0, stream>>>(w4, 256, 128, wp);
    k_uvgemm<128, 512, 256, true><<<512, 256, 0, stream>>>(xc + 128, wp, g4, b4, m4, v4, ub, xc + 256);
    k_edgemax<256, true><<<4096, 256, 0, stream>>>(ub, idx, g4, v4, xc + 256);

    // conv5: cast to bf16 (ub/idx now dead), MFMA GEMM + fused BN/LReLU/pool
    k_castbf<<<4096, 256, 0, stream>>>(xc, xcb, 1048576);
    k_castbf<<<256, 256, 0, stream>>>(w5, w5b, 65536);
    k_conv5mfma<<<1024, 256, 0, stream>>>(xcb, w5b, g5, b5, m5, v5, pmax, psum);
    k_poolfin<<<64, 256, 0, stream>>>(pmax, psum, p);

    // FC head
    k_fc<2048, 512, true,  false><<<32, 256, 0, stream>>>(p,  wl1, nullptr, g6, b6, m6, v6, h1);
    k_fc<512,  256, true,  true ><<<16, 256, 0, stream>>>(h1, wl2, bl2,     g7, b7, m7, v7, h2);
    k_fc<256,  101, false, true ><<<7,  256, 0, stream>>>(h2, wl3, bl3, nullptr, nullptr, nullptr, nullptr, (float*)d_out);
}

// Round 14
// 521.616 us; speedup vs baseline: 1.3029x; 1.1151x over previous
//
#include <hip/hip_runtime.h>
#include <cstdint>
#include <cmath>

#define DI __device__ __forceinline__

constexpr int BB = 16;      // batch
constexpr int NN = 1024;    // points
constexpr int KK = 20;      // neighbors
constexpr int NPT = BB*NN;  // total points 16384
constexpr float EPSF = 1e-5f;
constexpr float NEGINF = -3.0e38f;

DI float lrelu(float x){ return x >= 0.f ? x : 0.2f * x; }
DI float dot4(const float4 a, const float4 b){ return a.x*b.x + a.y*b.y + a.z*b.z + a.w*b.w; }
DI unsigned short f2bf(float x){            // round-to-nearest-even bf16
    uint32_t u = __float_as_uint(x);
    uint32_t r = (u + 0x7fffu + ((u >> 16) & 1u)) >> 16;
    return (unsigned short)r;
}

// wave64 max: 4 DPP row-rotate steps (VALU pipe) + 2 cross-row shuffles.
DI float wave_max64(float v){
    v = fmaxf(v, __int_as_float(__builtin_amdgcn_mov_dpp(__float_as_int(v), 0x121, 0xF, 0xF, true)));
    v = fmaxf(v, __int_as_float(__builtin_amdgcn_mov_dpp(__float_as_int(v), 0x122, 0xF, 0xF, true)));
    v = fmaxf(v, __int_as_float(__builtin_amdgcn_mov_dpp(__float_as_int(v), 0x124, 0xF, 0xF, true)));
    v = fmaxf(v, __int_as_float(__builtin_amdgcn_mov_dpp(__float_as_int(v), 0x128, 0xF, 0xF, true)));
    v = fmaxf(v, __shfl_xor(v, 16));
    v = fmaxf(v, __shfl_xor(v, 32));
    return v;
}

typedef __attribute__((ext_vector_type(8))) short short8v;  // bf16x8 MFMA fragment
typedef __attribute__((ext_vector_type(4))) float f32x4;

// ---------------------------------------------------------------- transpose x [B,3,N] -> xt0 [B,N,3], + sqnorm
__global__ void k_transpose(const float* __restrict__ x, float* __restrict__ xt, float* __restrict__ xx)
{
    int i = blockIdx.x * 256 + threadIdx.x;
    if (i >= NPT) return;
    int b = i >> 10, n = i & 1023;
    float a = x[(b*3 + 0)*NN + n];
    float c = x[(b*3 + 1)*NN + n];
    float d = x[(b*3 + 2)*NN + n];
    xt[i*3 + 0] = a; xt[i*3 + 1] = c; xt[i*3 + 2] = d;
    xx[i] = a*a + c*c + d*d;
}

// ---------------------------------------------------------------- kNN (R13 structure, unchanged)
template<int C>
__global__ __launch_bounds__(1024, 4) void k_knn(const float* __restrict__ src, int stride,
                                                 const float* __restrict__ xx,
                                                 int* __restrict__ idxo)
{
    constexpr bool SMALL = (C == 3);
    constexpr int CG = SMALL ? 1 : (C / 4);
    constexpr int TS = SMALL ? 5 : C;
    constexpr int NBUF = SMALL ? 1 : 2;
    constexpr int LPT = SMALL ? 1 : (128*CG/1024);
    __shared__ float tile[NBUF][128 * TS];

    const int tid  = threadIdx.x;
    const int lane = tid & 63;
    const int wv   = __builtin_amdgcn_readfirstlane(tid >> 6);
    const int b  = blockIdx.x >> 4;
    const int q0 = (blockIdx.x & 15) << 6;
    const int qbase = b*NN + q0 + (wv << 2);

    const float* qp0 = src + (size_t)(qbase + 0)*stride;
    const float* qp1 = src + (size_t)(qbase + 1)*stride;
    const float* qp2 = src + (size_t)(qbase + 2)*stride;
    const float* qp3 = src + (size_t)(qbase + 3)*stride;

    float xxq[4];
    #pragma unroll
    for (int q = 0; q < 4; ++q) xxq[q] = xx[qbase + q];

    float val[4][16];

    if constexpr (SMALL){
        #pragma unroll
        for (int t = 0; t < 8; ++t){
            __syncthreads();
            for (int i = tid; i < 128*3; i += 1024){
                int row = i / 3, c = i % 3;
                tile[0][row*TS + c] = src[(size_t)(b*NN + t*128 + row)*stride + c];
            }
            __syncthreads();
            float c0a = tile[0][lane*TS+0], c0b = tile[0][lane*TS+1], c0c = tile[0][lane*TS+2];
            float c1a = tile[0][(64+lane)*TS+0], c1b = tile[0][(64+lane)*TS+1], c1c = tile[0][(64+lane)*TS+2];
            float q00 = qp0[0], q01 = qp0[1], q02 = qp0[2];
            float q10 = qp1[0], q11 = qp1[1], q12 = qp1[2];
            float q20 = qp2[0], q21 = qp2[1], q22 = qp2[2];
            float q30 = qp3[0], q31 = qp3[1], q32 = qp3[2];
            float xxm0 = xx[b*NN + t*128 + lane];
            float xxm1 = xx[b*NN + t*128 + 64 + lane];
            val[0][2*t]   = 2.f*(q00*c0a + q01*c0b + q02*c0c) - xxq[0] - xxm0;
            val[0][2*t+1] = 2.f*(q00*c1a + q01*c1b + q02*c1c) - xxq[0] - xxm1;
            val[1][2*t]   = 2.f*(q10*c0a + q11*c0b + q12*c0c) - xxq[1] - xxm0;
            val[1][2*t+1] = 2.f*(q10*c1a + q11*c1b + q12*c1c) - xxq[1] - xxm1;
            val[2][2*t]   = 2.f*(q20*c0a + q21*c0b + q22*c0c) - xxq[2] - xxm0;
            val[2][2*t+1] = 2.f*(q20*c1a + q21*c1b + q22*c1c) - xxq[2] - xxm1;
            val[3][2*t]   = 2.f*(q30*c0a + q31*c0b + q32*c0c) - xxq[3] - xxm0;
            val[3][2*t+1] = 2.f*(q30*c1a + q31*c1b + q32*c1c) - xxq[3] - xxm1;
        }
    } else {
        float4 nx[LPT];
        #pragma unroll
        for (int k = 0; k < LPT; ++k){
            int i = tid + k*1024;
            int row = i / CG, cg = i % CG;
            nx[k] = *(const float4*)(src + (size_t)(b*NN + row)*stride + cg*4);
        }
        #pragma unroll
        for (int k = 0; k < LPT; ++k){
            int i = tid + k*1024;
            int row = i / CG, cg = i % CG;
            int p = cg ^ (row & (CG - 1));
            *(float4*)(&tile[0][row*TS + p*4]) = nx[k];
        }

        for (int t = 0; t < 8; ++t){
            __syncthreads();
            if (t < 7){
                #pragma unroll
                for (int k = 0; k < LPT; ++k){
                    int i = tid + k*1024;
                    int row = i / CG, cg = i % CG;
                    nx[k] = *(const float4*)(src + (size_t)(b*NN + (t+1)*128 + row)*stride + cg*4);
                }
            }
            const float* tb = tile[t & 1];

            float acc[4][2];
            #pragma unroll
            for (int q = 0; q < 4; ++q){ acc[q][0] = 0.f; acc[q][1] = 0.f; }
            const int sw = lane & (CG - 1);
            #pragma unroll 2
            for (int cg0 = 0; cg0 < CG; ++cg0){
                float4 cf0 = *(const float4*)(tb + lane*TS      + ((cg0 ^ sw) << 2));
                float4 cf1 = *(const float4*)(tb + (64+lane)*TS + ((cg0 ^ sw) << 2));
                float4 qf0 = *(const float4*)(qp0 + (cg0 << 2));
                float4 qf1 = *(const float4*)(qp1 + (cg0 << 2));
                float4 qf2 = *(const float4*)(qp2 + (cg0 << 2));
                float4 qf3 = *(const float4*)(qp3 + (cg0 << 2));
                acc[0][0] += dot4(qf0, cf0); acc[0][1] += dot4(qf0, cf1);
                acc[1][0] += dot4(qf1, cf0); acc[1][1] += dot4(qf1, cf1);
                acc[2][0] += dot4(qf2, cf0); acc[2][1] += dot4(qf2, cf1);
                acc[3][0] += dot4(qf3, cf0); acc[3][1] += dot4(qf3, cf1);
            }
            float xxm0 = xx[b*NN + t*128 + lane];
            float xxm1 = xx[b*NN + t*128 + 64 + lane];
            #pragma unroll
            for (int q = 0; q < 4; ++q){
                val[q][2*t]   = 2.f*acc[q][0] - xxq[q] - xxm0;
                val[q][2*t+1] = 2.f*acc[q][1] - xxq[q] - xxm1;
            }

            if (t < 7){
                float* wb = &tile[(t+1) & 1][0];
                #pragma unroll
                for (int k = 0; k < LPT; ++k){
                    int i = tid + k*1024;
                    int row = i / CG, cg = i % CG;
                    int p = cg ^ (row & (CG - 1));
                    *(float4*)(&wb[row*TS + p*4]) = nx[k];
                }
            }
        }
    }

    // ---- selection per query: bitonic sort + DPP tournament ----
    #pragma unroll
    for (int q = 0; q < 4; ++q){
        const int orow = (qbase + q) * KK;

        float s[16];
        #pragma unroll
        for (int j = 0; j < 16; ++j) s[j] = val[q][j];
        #pragma unroll
        for (int k = 2; k <= 16; k <<= 1){
            #pragma unroll
            for (int jj = k >> 1; jj > 0; jj >>= 1){
                #pragma unroll
                for (int i = 0; i < 16; ++i){
                    int l = i ^ jj;
                    if (l > i){
                        float a = s[i], c = s[l];
                        float mx = fmaxf(a, c), mn = fminf(a, c);
                        bool up = ((i & k) == 0);
                        s[i] = up ? mx : mn;
                        s[l] = up ? mn : mx;
                    }
                }
            }
        }

        float T = NEGINF;
        for (int it = 0; it < 21; ++it){
            float m = wave_max64(s[0]);
            T = m;
            unsigned long long mk = __ballot(s[0] == m);
            int wl = __ffsll(mk) - 1;
            bool adv = (lane == wl);
            #pragma unroll
            for (int j = 0; j < 15; ++j) s[j] = adv ? s[j+1] : s[j];
            s[15] = adv ? NEGINF : s[15];
        }

        int cnt = 0;
        #pragma unroll
        for (int j = 0; j < 16; ++j) cnt += (val[q][j] > T) ? 1 : 0;
        int off = cnt;
        #pragma unroll
        for (int d = 1; d < 64; d <<= 1){
            int tt = __shfl_up(off, d);
            if (lane >= d) off += tt;
        }
        int total = __shfl(off, 63);
        int pos = orow + off - cnt;
        #pragma unroll
        for (int j = 0; j < 16; ++j){
            if (val[q][j] > T){ idxo[pos] = j*64 + lane; ++pos; }
        }
        if (total < KK){
            int rem = KK - total;
            int prior = 0;
            #pragma unroll
            for (int j = 0; j < 16; ++j){
                unsigned long long mk = __ballot(val[q][j] == T);
                int below = __popcll(mk & ((1ull << lane) - 1ull));
                if ((val[q][j] == T) && (prior + below < rem))
                    idxo[orow + total + prior + below] = j*64 + lane;
                prior += __popcll(mk);
            }
        }
    }
}

// ---------------------------------------------------------------- u/v GEMM (fp32; wprep folded into weight staging)
// K = C (input dims); weight rows: row<O -> Wj[row], row>=O -> Wi-Wj of row-O.
template<int K, int M2, int O, bool UB16>
__global__ __launch_bounds__(256) void k_uvgemm(const float* __restrict__ srcp,
    const float* __restrict__ w,
    const float* __restrict__ g, const float* __restrict__ bp,
    const float* __restrict__ mp, const float* __restrict__ vp,
    float* __restrict__ ub, float* __restrict__ xcv)
{
    constexpr int LD = 136;
    __shared__ float wl[16*LD];
    __shared__ float xl[16*LD];
    const int tid = threadIdx.x;
    const int nt = blockIdx.x & 127;
    const int mt = blockIdx.x >> 7;
    const int to = tid >> 4, tn = tid & 15;

    float acc[8][8];
    #pragma unroll
    for (int i = 0; i < 8; ++i)
        #pragma unroll
        for (int j = 0; j < 8; ++j) acc[i][j] = 0.f;

    for (int c0 = 0; c0 < K; c0 += 16){
        __syncthreads();
        #pragma unroll
        for (int p = 0; p < 2; ++p){
            int fi = tid + (p << 8);
            int row = fi >> 2, cq = (fi & 3) << 2;
            int gr = mt*128 + row;
            float4 wv;
            if (gr < O){
                wv = *(const float4*)(w + (size_t)gr*(2*K) + c0 + cq);
            } else {
                int o = gr - O;
                float4 a  = *(const float4*)(w + (size_t)o*(2*K) + c0 + cq);
                float4 bq = *(const float4*)(w + (size_t)o*(2*K) + K + c0 + cq);
                wv = make_float4(bq.x-a.x, bq.y-a.y, bq.z-a.z, bq.w-a.w);
            }
            wl[(cq+0)*LD + row] = wv.x;
            wl[(cq+1)*LD + row] = wv.y;
            wl[(cq+2)*LD + row] = wv.z;
            wl[(cq+3)*LD + row] = wv.w;
            float4 xv = *(const float4*)(srcp + (size_t)(nt*128 + row)*512 + c0 + cq);
            xl[(cq+0)*LD + row] = xv.x;
            xl[(cq+1)*LD + row] = xv.y;
            xl[(cq+2)*LD + row] = xv.z;
            xl[(cq+3)*LD + row] = xv.w;
        }
        __syncthreads();
        #pragma unroll
        for (int cc = 0; cc < 16; ++cc){
            float4 a0 = *(const float4*)(wl + cc*LD + to*8);
            float4 a1 = *(const float4*)(wl + cc*LD + to*8 + 4);
            float4 b0 = *(const float4*)(xl + cc*LD + tn*8);
            float4 b1 = *(const float4*)(xl + cc*LD + tn*8 + 4);
            float av[8] = {a0.x,a0.y,a0.z,a0.w,a1.x,a1.y,a1.z,a1.w};
            float bv[8] = {b0.x,b0.y,b0.z,b0.w,b1.x,b1.y,b1.z,b1.w};
            #pragma unroll
            for (int i = 0; i < 8; ++i)
                #pragma unroll
                for (int j = 0; j < 8; ++j) acc[i][j] += av[i]*bv[j];
        }
    }

    const int mbase = mt*128 + to*8;
    const bool isu = mbase < O;
    float mult[8], add[8];
    #pragma unroll
    for (int i = 0; i < 8; ++i){
        int m = mbase + i;
        if (isu){
            float s = g[m] / sqrtf(vp[m] + EPSF);
            mult[i] = (s >= 0.f) ? 1.f : -1.f;
            add[i]  = 0.f;
        } else {
            int o = m - O;
            float s = g[o] / sqrtf(vp[o] + EPSF);
            mult[i] = s;
            add[i]  = bp[o] - mp[o]*s;
        }
    }
    #pragma unroll
    for (int j = 0; j < 8; ++j){
        int pt = nt*128 + tn*8 + j;
        float4 v0, v1;
        v0.x = fmaf(mult[0], acc[0][j], add[0]);
        v0.y = fmaf(mult[1], acc[1][j], add[1]);
        v0.z = fmaf(mult[2], acc[2][j], add[2]);
        v0.w = fmaf(mult[3], acc[3][j], add[3]);
        v1.x = fmaf(mult[4], acc[4][j], add[4]);
        v1.y = fmaf(mult[5], acc[5][j], add[5]);
        v1.z = fmaf(mult[6], acc[6][j], add[6]);
        v1.w = fmaf(mult[7], acc[7][j], add[7]);
        if (isu){
            if constexpr (UB16){
                union { unsigned short u[8]; uint4 v; } o;
                o.u[0] = f2bf(v0.x); o.u[1] = f2bf(v0.y); o.u[2] = f2bf(v0.z); o.u[3] = f2bf(v0.w);
                o.u[4] = f2bf(v1.x); o.u[5] = f2bf(v1.y); o.u[6] = f2bf(v1.z); o.u[7] = f2bf(v1.w);
                *(uint4*)((unsigned short*)ub + (size_t)pt*O + mbase) = o.v;
            } else {
                float* d = ub + (size_t)pt*O + mbase;
                *(float4*)(d)     = v0;
                *(float4*)(d + 4) = v1;
            }
        } else {
            float* d = xcv + (size_t)pt*512 + (mbase - O);
            *(float4*)(d)     = v0;
            *(float4*)(d + 4) = v1;
        }
    }
}

// ---------------------------------------------------------------- layer-1 u/v (C=3) direct (wprep inlined)
__global__ __launch_bounds__(256) void k_uv3(const float* __restrict__ xt,
    const float* __restrict__ w,
    const float* __restrict__ g, const float* __restrict__ bp,
    const float* __restrict__ mp, const float* __restrict__ vp,
    float* __restrict__ ub, float* __restrict__ xcv)
{
    __shared__ float wpl[128*3];
    __shared__ float mult[128], add[128];
    const int tid = threadIdx.x;
    if (tid < 128){
        int m = tid;
        if (m < 64){
            float s = g[m] / sqrtf(vp[m] + EPSF);
            mult[m] = (s >= 0.f) ? 1.f : -1.f;
            add[m]  = 0.f;
        } else {
            int o = m - 64;
            float s = g[o] / sqrtf(vp[o] + EPSF);
            mult[m] = s;
            add[m]  = bp[o] - mp[o]*s;
        }
    }
    for (int i = tid; i < 128*3; i += 256){
        int m = i / 3, c = i % 3;
        wpl[i] = (m < 64) ? w[m*6 + c] : (w[(m-64)*6 + 3 + c] - w[(m-64)*6 + c]);
    }
    __syncthreads();

    const int ptl = tid >> 5, mg = tid & 31;
    const int m0 = mg * 4;
    const int pt = blockIdx.x*8 + ptl;
    float x0 = xt[pt*3+0], x1 = xt[pt*3+1], x2 = xt[pt*3+2];
    float4 v4;
    float tmp[4];
    #pragma unroll
    for (int r = 0; r < 4; ++r){
        int m = m0 + r;
        float a = wpl[m*3+0]*x0 + wpl[m*3+1]*x1 + wpl[m*3+2]*x2;
        tmp[r] = fmaf(mult[m], a, add[m]);
    }
    v4.x = tmp[0]; v4.y = tmp[1]; v4.z = tmp[2]; v4.w = tmp[3];
    if (m0 < 64) *(float4*)(ub + (size_t)pt*64 + m0) = v4;
    else         *(float4*)(xcv + (size_t)pt*512 + (m0 - 64)) = v4;
}

// ---------------------------------------------------------------- layer-4 u/v via bf16 MFMA (downstream is all bf16)
// M2=512 rows (256 u + 256 v), K=128, N=16384 pts. On-the-fly wprep+cast.
__global__ __launch_bounds__(256) void k_uvmfma(const float* __restrict__ xc,
    const float* __restrict__ w,
    const float* __restrict__ g, const float* __restrict__ bp,
    const float* __restrict__ mp, const float* __restrict__ vp,
    unsigned short* __restrict__ ub, float* __restrict__ vout)
{
    __shared__ __align__(16) short lA[128*32];
    __shared__ __align__(16) short lB[128*32];
    __shared__ float scl[128], adl[128];

    const int tid = threadIdx.x;
    const int lane = tid & 63, wave = tid >> 6;
    const int wm = wave >> 1, wn = wave & 1;
    const int mt = blockIdx.x >> 7;          // 0..3 (0,1=u  2,3=v)
    const int nt = blockIdx.x & 127;         // pt tile

    if (tid < 128){
        int m = mt*128 + tid;
        if (m < 256){
            float s = g[m] / sqrtf(vp[m] + EPSF);
            scl[tid] = (s >= 0.f) ? 1.f : -1.f;
            adl[tid] = 0.f;
        } else {
            int o = m - 256;
            float s = g[o] / sqrtf(vp[o] + EPSF);
            scl[tid] = s;
            adl[tid] = bp[o] - mp[o]*s;
        }
    }

    f32x4 acc[4][4];
    #pragma unroll
    for (int i = 0; i < 4; ++i)
        #pragma unroll
        for (int j = 0; j < 4; ++j) acc[i][j] = (f32x4){0.f,0.f,0.f,0.f};

    const bool isu = (mt < 2);

    for (int ks = 0; ks < 4; ++ks){
        __syncthreads();
        #pragma unroll
        for (int p = 0; p < 2; ++p){
            int off = p*256 + tid;
            int row = off >> 2;
            int slot = off & 3;
            int ssl = slot ^ (row & 3);
            // A: weight row with transform + cast
            float va[8];
            if (isu){
                int m = mt*128 + row;
                const float* sp = w + (size_t)m*256 + ks*32 + slot*8;
                float4 a0 = *(const float4*)(sp);
                float4 a1 = *(const float4*)(sp + 4);
                va[0]=a0.x; va[1]=a0.y; va[2]=a0.z; va[3]=a0.w;
                va[4]=a1.x; va[5]=a1.y; va[6]=a1.z; va[7]=a1.w;
            } else {
                int o = (mt-2)*128 + row;
                const float* sp = w + (size_t)o*256 + ks*32 + slot*8;
                float4 a0 = *(const float4*)(sp);
                float4 a1 = *(const float4*)(sp + 4);
                float4 b0 = *(const float4*)(sp + 128);
                float4 b1 = *(const float4*)(sp + 132);
                va[0]=b0.x-a0.x; va[1]=b0.y-a0.y; va[2]=b0.z-a0.z; va[3]=b0.w-a0.w;
                va[4]=b1.x-a1.x; va[5]=b1.y-a1.y; va[6]=b1.z-a1.z; va[7]=b1.w-a1.w;
            }
            union { unsigned short u[8]; uint4 v; } oa;
            #pragma unroll
            for (int e = 0; e < 8; ++e) oa.u[e] = f2bf(va[e]);
            *(uint4*)(lA + row*32 + ssl*8) = oa.v;
            // B: xc channels [128,256) fp32 -> bf16
            const float* spb = xc + (size_t)(nt*128 + row)*512 + 128 + ks*32 + slot*8;
            float4 x0 = *(const float4*)(spb);
            float4 x1 = *(const float4*)(spb + 4);
            union { unsigned short u[8]; uint4 v; } ob;
            ob.u[0]=f2bf(x0.x); ob.u[1]=f2bf(x0.y); ob.u[2]=f2bf(x0.z); ob.u[3]=f2bf(x0.w);
            ob.u[4]=f2bf(x1.x); ob.u[5]=f2bf(x1.y); ob.u[6]=f2bf(x1.z); ob.u[7]=f2bf(x1.w);
            *(uint4*)(lB + row*32 + ssl*8) = ob.v;
        }
        __syncthreads();

        short8v afr[4], bfr[4];
        #pragma unroll
        for (int i = 0; i < 4; ++i){
            int row = wm*64 + i*16 + (lane & 15);
            int sl  = (lane >> 4) ^ (row & 3);
            afr[i] = *(const short8v*)(lA + row*32 + sl*8);
        }
        #pragma unroll
        for (int j = 0; j < 4; ++j){
            int row = wn*64 + j*16 + (lane & 15);
            int sl  = (lane >> 4) ^ (row & 3);
            bfr[j] = *(const short8v*)(lB + row*32 + sl*8);
        }
        #pragma unroll
        for (int i = 0; i < 4; ++i)
            #pragma unroll
            for (int j = 0; j < 4; ++j)
                acc[i][j] = __builtin_amdgcn_mfma_f32_16x16x32_bf16(afr[i], bfr[j], acc[i][j], 0, 0, 0);
    }

    // epilogue: C/D mapping col=lane&15 (pt), row=(lane>>4)*4 + r
    #pragma unroll
    for (int i = 0; i < 4; ++i){
        #pragma unroll
        for (int j = 0; j < 4; ++j){
            int m_loc = wm*64 + i*16 + (lane >> 4)*4;
            int pt    = nt*128 + wn*64 + j*16 + (lane & 15);
            if (isu){
                union { unsigned short u[4]; uint2 v; } o;
                #pragma unroll
                for (int r = 0; r < 4; ++r)
                    o.u[r] = f2bf(scl[m_loc + r] * acc[i][j][r]);
                *(uint2*)(ub + (size_t)pt*256 + mt*128 + m_loc) = o.v;
            } else {
                float4 y;
                y.x = fmaf(scl[m_loc+0], acc[i][j][0], adl[m_loc+0]);
                y.y = fmaf(scl[m_loc+1], acc[i][j][1], adl[m_loc+1]);
                y.z = fmaf(scl[m_loc+2], acc[i][j][2], adl[m_loc+2]);
                y.w = fmaf(scl[m_loc+3], acc[i][j][3], adl[m_loc+3]);
                *(float4*)(vout + (size_t)pt*512 + (mt-2)*128 + m_loc) = y;
            }
        }
    }
}

// ---------------------------------------------------------------- combine: out = lrelu(|s| * max_k u'[j_k] + v'), optional next-layer norms
template<int O, bool UB16, bool NORM>
__global__ __launch_bounds__(256) void k_edgemax(const float* __restrict__ ub,
    const int* __restrict__ idxg,
    const float* __restrict__ g, const float* __restrict__ vp,
    float* __restrict__ xcv, float* __restrict__ xxout)
{
    constexpr int TPP = O / 4;
    constexpr int PPB = 256 / TPP;
    const int tid = threadIdx.x;
    const int pt  = blockIdx.x*PPB + tid / TPP;
    const int oq  = (tid % TPP) * 4;
    const int bb  = pt & ~(NN-1);

    int nb[KK];
    #pragma unroll
    for (int k = 0; k < KK; ++k) nb[k] = idxg[pt*KK + k];

    float4 mx;
    if constexpr (UB16){
        const unsigned short* ubh = (const unsigned short*)ub;
        uint2 r0 = *(const uint2*)(ubh + (size_t)(bb + nb[0])*O + oq);
        mx.x = __uint_as_float(r0.x << 16);
        mx.y = __uint_as_float(r0.x & 0xffff0000u);
        mx.z = __uint_as_float(r0.y << 16);
        mx.w = __uint_as_float(r0.y & 0xffff0000u);
        #pragma unroll
        for (int k = 1; k < KK; ++k){
            uint2 r = *(const uint2*)(ubh + (size_t)(bb + nb[k])*O + oq);
            mx.x = fmaxf(mx.x, __uint_as_float(r.x << 16));
            mx.y = fmaxf(mx.y, __uint_as_float(r.x & 0xffff0000u));
            mx.z = fmaxf(mx.z, __uint_as_float(r.y << 16));
            mx.w = fmaxf(mx.w, __uint_as_float(r.y & 0xffff0000u));
        }
    } else {
        mx = *(const float4*)(ub + (size_t)(bb + nb[0])*O + oq);
        #pragma unroll
        for (int k = 1; k < KK; ++k){
            float4 u = *(const float4*)(ub + (size_t)(bb + nb[k])*O + oq);
            mx.x = fmaxf(mx.x, u.x); mx.y = fmaxf(mx.y, u.y);
            mx.z = fmaxf(mx.z, u.z); mx.w = fmaxf(mx.w, u.w);
        }
    }
    float4 gv = *(const float4*)(g + oq);
    float4 vv = *(const float4*)(vp + oq);
    float4 as;
    as.x = fabsf(gv.x / sqrtf(vv.x + EPSF));
    as.y = fabsf(gv.y / sqrtf(vv.y + EPSF));
    as.z = fabsf(gv.z / sqrtf(vv.z + EPSF));
    as.w = fabsf(gv.w / sqrtf(vv.w + EPSF));
    float* d = xcv + (size_t)pt*512 + oq;
    float4 vr = *(const float4*)(d);
    float4 y;
    y.x = lrelu(fmaf(as.x, mx.x, vr.x));
    y.y = lrelu(fmaf(as.y, mx.y, vr.y));
    y.z = lrelu(fmaf(as.z, mx.z, vr.z));
    y.w = lrelu(fmaf(as.w, mx.w, vr.w));
    *(float4*)(d) = y;

    if constexpr (NORM){
        float part = dot4(y, y);
        #pragma unroll
        for (int dd = 1; dd < TPP; dd <<= 1) part += __shfl_xor(part, dd);
        if ((tid & (TPP - 1)) == 0) xxout[pt] = part;
    }
}

// ---------------------------------------------------------------- conv5 bf16 MFMA GEMM (fp32 sources, on-the-fly cast) + pool partials
__global__ __launch_bounds__(256) void k_conv5mfma(const float* __restrict__ xc,
    const float* __restrict__ w5,
    const float* __restrict__ g, const float* __restrict__ bp,
    const float* __restrict__ mp, const float* __restrict__ vp,
    float* __restrict__ pmax, float* __restrict__ psum)
{
    __shared__ __align__(16) short lA[128*32];
    __shared__ __align__(16) short lB[128*32];
    __shared__ float scl[128], adl[128];
    __shared__ float red[2][128][2];

    const int tid = threadIdx.x;
    const int lane = tid & 63, wave = tid >> 6;
    const int wm = wave >> 1, wn = wave & 1;
    const int b  = blockIdx.x >> 6;
    const int mt = (blockIdx.x >> 3) & 7;
    const int nt = blockIdx.x & 7;

    if (tid < 128){
        int o = mt*128 + tid;
        float s = g[o] / sqrtf(vp[o] + EPSF);
        scl[tid] = s;
        adl[tid] = bp[o] - mp[o]*s;
    }

    f32x4 acc[4][4];
    #pragma unroll
    for (int i = 0; i < 4; ++i)
        #pragma unroll
        for (int j = 0; j < 4; ++j) acc[i][j] = (f32x4){0.f,0.f,0.f,0.f};

    const float* gA = w5 + (size_t)(mt*128)*512;
    const float* gB = xc + (size_t)(b*1024 + nt*128)*512;

    for (int ks = 0; ks < 16; ++ks){
        __syncthreads();
        #pragma unroll
        for (int p = 0; p < 2; ++p){
            int off = p*256 + tid;
            int row = off >> 2;
            int slot = off & 3;
            int ssl = slot ^ (row & 3);
            const float* spa = gA + (size_t)row*512 + ks*32 + slot*8;
            float4 a0 = *(const float4*)(spa);
            float4 a1 = *(const float4*)(spa + 4);
            union { unsigned short u[8]; uint4 v; } oa;
            oa.u[0]=f2bf(a0.x); oa.u[1]=f2bf(a0.y); oa.u[2]=f2bf(a0.z); oa.u[3]=f2bf(a0.w);
            oa.u[4]=f2bf(a1.x); oa.u[5]=f2bf(a1.y); oa.u[6]=f2bf(a1.z); oa.u[7]=f2bf(a1.w);
            *(uint4*)(lA + row*32 + ssl*8) = oa.v;
            const float* spb = gB + (size_t)row*512 + ks*32 + slot*8;
            float4 x0 = *(const float4*)(spb);
            float4 x1 = *(const float4*)(spb + 4);
            union { unsigned short u[8]; uint4 v; } ob;
            ob.u[0]=f2bf(x0.x); ob.u[1]=f2bf(x0.y); ob.u[2]=f2bf(x0.z); ob.u[3]=f2bf(x0.w);
            ob.u[4]=f2bf(x1.x); ob.u[5]=f2bf(x1.y); ob.u[6]=f2bf(x1.z); ob.u[7]=f2bf(x1.w);
            *(uint4*)(lB + row*32 + ssl*8) = ob.v;
        }
        __syncthreads();

        short8v afr[4], bfr[4];
        #pragma unroll
        for (int i = 0; i < 4; ++i){
            int row = wm*64 + i*16 + (lane & 15);
            int sl  = (lane >> 4) ^ (row & 3);
            afr[i] = *(const short8v*)(lA + row*32 + sl*8);
        }
        #pragma unroll
        for (int j = 0; j < 4; ++j){
            int row = wn*64 + j*16 + (lane & 15);
            int sl  = (lane >> 4) ^ (row & 3);
            bfr[j] = *(const short8v*)(lB + row*32 + sl*8);
        }
        #pragma unroll
        for (int i = 0; i < 4; ++i)
            #pragma unroll
            for (int j = 0; j < 4; ++j)
                acc[i][j] = __builtin_amdgcn_mfma_f32_16x16x32_bf16(afr[i], bfr[j], acc[i][j], 0, 0, 0);
    }

    float emx[4][4], esm[4][4];
    #pragma unroll
    for (int i = 0; i < 4; ++i){
        #pragma unroll
        for (int r = 0; r < 4; ++r){
            int m_loc = wm*64 + i*16 + (lane >> 4)*4 + r;
            float s = scl[m_loc], t = adl[m_loc];
            float mx = NEGINF, sm = 0.f;
            #pragma unroll
            for (int j = 0; j < 4; ++j){
                float y = lrelu(fmaf(acc[i][j][r], s, t));
                mx = fmaxf(mx, y); sm += y;
            }
            #pragma unroll
            for (int d = 1; d < 16; d <<= 1){
                mx = fmaxf(mx, __shfl_xor(mx, d));
                sm += __shfl_xor(sm, d);
            }
            emx[i][r] = mx; esm[i][r] = sm;
        }
    }
    if ((lane & 15) == 0){
        #pragma unroll
        for (int i = 0; i < 4; ++i)
            #pragma unroll
            for (int r = 0; r < 4; ++r){
                int m_loc = wm*64 + i*16 + (lane >> 4)*4 + r;
                red[wn][m_loc][0] = emx[i][r];
                red[wn][m_loc][1] = esm[i][r];
            }
    }
    __syncthreads();
    if (tid < 128){
        float mx = fmaxf(red[0][tid][0], red[1][tid][0]);
        float sm = red[0][tid][1] + red[1][tid][1];
        int o = mt*128 + tid;
        pmax[(size_t)(b*NN + o)*8 + nt] = mx;
        psum[(size_t)(b*NN + o)*8 + nt] = sm;
    }
}

__global__ void k_poolfin(const float* __restrict__ pmax, const float* __restrict__ psum,
                          float* __restrict__ p)
{
    int i = blockIdx.x*256 + threadIdx.x;
    if (i >= NPT) return;
    int b = i >> 10, o = i & 1023;
    float mx = NEGINF, sm = 0.f;
    #pragma unroll
    for (int t = 0; t < 8; ++t){ mx = fmaxf(mx, pmax[(size_t)i*8 + t]); sm += psum[(size_t)i*8 + t]; }
    p[b*2048 + o]        = mx;
    p[b*2048 + 1024 + o] = sm * (1.f/1024.f);
}

// ---------------------------------------------------------------- small FC layers
template<int IN, int O, bool HASBN, bool HASBIAS>
__global__ void k_fc(const float* __restrict__ in, const float* __restrict__ W,
                     const float* __restrict__ bias,
                     const float* __restrict__ g, const float* __restrict__ bp,
                     const float* __restrict__ mp, const float* __restrict__ vp,
                     float* __restrict__ out)
{
    int i = blockIdx.x*256 + threadIdx.x;
    if (i >= BB*O) return;
    int b = i / O, o = i % O;
    const float* wr = W  + (size_t)o*IN;
    const float* ir = in + (size_t)b*IN;
    float s = 0.f;
    #pragma unroll 4
    for (int c = 0; c < IN; c += 4){
        float4 a = *(const float4*)(wr + c);
        float4 x = *(const float4*)(ir + c);
        s += dot4(a, x);
    }
    if (HASBIAS) s += bias[o];
    if (HASBN){
        float sc = g[o] / sqrtf(vp[o] + EPSF);
        s = (s - mp[o])*sc + bp[o];
        s = lrelu(s);
    }
    out[(size_t)b*O + o] = s;
}

// ---------------------------------------------------------------- launch
extern "C" void kernel_launch(void* const* d_in, const int* in_sizes, int n_in,
                              void* d_out, int out_size, void* d_ws, size_t ws_size,
                              hipStream_t stream)
{
    (void)in_sizes; (void)n_in; (void)out_size; (void)ws_size;
    const float* x   = (const float*)d_in[0];
    const float* w1  = (const float*)d_in[1];
    const float* w2  = (const float*)d_in[2];
    const float* w3  = (const float*)d_in[3];
    const float* w4  = (const float*)d_in[4];
    const float* w5  = (const float*)d_in[5];
    const float* wl1 = (const float*)d_in[6];
    const float* wl2 = (const float*)d_in[7];
    const float* wl3 = (const float*)d_in[8];
    const float* bl2 = (const float*)d_in[9];
    const float* bl3 = (const float*)d_in[10];
    const float* g1 = (const float*)d_in[11]; const float* b1 = (const float*)d_in[12];
    const float* m1 = (const float*)d_in[13]; const float* v1 = (const float*)d_in[14];
    const float* g2 = (const float*)d_in[15]; const float* b2 = (const float*)d_in[16];
    const float* m2 = (const float*)d_in[17]; const float* v2 = (const float*)d_in[18];
    const float* g3 = (const float*)d_in[19]; const float* b3 = (const float*)d_in[20];
    const float* m3 = (const float*)d_in[21]; const float* v3 = (const float*)d_in[22];
    const float* g4 = (const float*)d_in[23]; const float* b4 = (const float*)d_in[24];
    const float* m4 = (const float*)d_in[25]; const float* v4 = (const float*)d_in[26];
    const float* g5 = (const float*)d_in[27]; const float* b5 = (const float*)d_in[28];
    const float* m5 = (const float*)d_in[29]; const float* v5 = (const float*)d_in[30];
    const float* g6 = (const float*)d_in[31]; const float* b6 = (const float*)d_in[32];
    const float* m6 = (const float*)d_in[33]; const float* v6 = (const float*)d_in[34];
    const float* g7 = (const float*)d_in[35]; const float* b7 = (const float*)d_in[36];
    const float* m7 = (const float*)d_in[37]; const float* v7 = (const float*)d_in[38];

    float* wsf  = (float*)d_ws;
    float* xt0  = wsf;                    // 49152
    float* xc   = xt0 + 49152;            // 8388608
    float* xx   = xc + 8388608;           // 16384
    int*   idx  = (int*)(xx + 16384);     // 327680 ints
    float* pmax = (float*)(idx + 327680); // 131072
    float* psum = pmax + 131072;          // 131072
    float* p    = psum + 131072;          // 32768
    float* h1   = p + 32768;              // 8192
    float* h2   = h1 + 8192;              // 4096
    float* ub   = h2 + 4096;              // 4194304 (l4 uses it as bf16)

    k_transpose<<<64, 256, 0, stream>>>(x, xt0, xx);

    // block 1: C=3 -> O=64 (channels 0..63)
    k_knn<3><<<256, 1024, 0, stream>>>(xt0, 3, xx, idx);
    k_uv3<<<2048, 256, 0, stream>>>(xt0, w1, g1, b1, m1, v1, ub, xc);
    k_edgemax<64, false, true><<<1024, 256, 0, stream>>>(ub, idx, g1, v1, xc, xx);

    // block 2: C=64 -> O=64 (channels 64..127)
    k_knn<64><<<256, 1024, 0, stream>>>(xc, 512, xx, idx);
    k_uvgemm<64, 128, 64, false><<<128, 256, 0, stream>>>(xc, w2, g2, b2, m2, v2, ub, xc + 64);
    k_edgemax<64, false, true><<<1024, 256, 0, stream>>>(ub, idx, g2, v2, xc + 64, xx);

    // block 3: C=64 -> O=128 (channels 128..255)
    k_knn<64><<<256, 1024, 0, stream>>>(xc + 64, 512, xx, idx);
    k_uvgemm<64, 256, 128, false><<<256, 256, 0, stream>>>(xc + 64, w3, g3, b3, m3, v3, ub, xc + 128);
    k_edgemax<128, false, true><<<2048, 256, 0, stream>>>(ub, idx, g3, v3, xc + 128, xx);

    // block 4: C=128 -> O=256 (channels 256..511) — bf16 MFMA u/v, bf16 u-table
    k_knn<128><<<256, 1024, 0, stream>>>(xc + 128, 512, xx, idx);
    k_uvmfma<<<512, 256, 0, stream>>>(xc, w4, g4, b4, m4, v4, (unsigned short*)ub, xc + 256);
    k_edgemax<256, true, false><<<4096, 256, 0, stream>>>(ub, idx, g4, v4, xc + 256, nullptr);

    // conv5 (stages fp32 -> bf16 on the fly) + pooling
    k_conv5mfma<<<1024, 256, 0, stream>>>(xc, w5, g5, b5, m5, v5, pmax, psum);
    k_poolfin<<<64, 256, 0, stream>>>(pmax, psum, p);

    // FC head
    k_fc<2048, 512, true,  false><<<32, 256, 0, stream>>>(p,  wl1, nullptr, g6, b6, m6, v6, h1);
    k_fc<512,  256, true,  true ><<<16, 256, 0, stream>>>(h1, wl2, bl2,     g7, b7, m7, v7, h2);
    k_fc<256,  101, false, true ><<<7,  256, 0, stream>>>(h2, wl3, bl3, nullptr, nullptr, nullptr, nullptr, (float*)d_out);
}